// Round 3
// baseline (1375.304 us; speedup 1.0000x reference)
//
#include <hip/hip_runtime.h>
#include <cstdint>

// Problem constants (fixed by setup_inputs: H=480, W=1024, S=32, margin=10, step=4)
#define HH 480
#define WW 1024
#define SS 32
#define HW (HH*WW)              // 491520
#define MARGIN 10
#define STEP 4
#define GYC 116                 // len(arange(10, 471, 4))
#define GXC 252                 // len(arange(10, 1015, 4))
#define GG (GYC*GXC)            // 29232 grid candidates
#define NSLOT (2*HH*WW/(STEP*STEP))  // 61440 trajectory slots
#define NBLK (NSLOT/256)        // 240 blocks -> co-resident on 256 CUs
#define NWAVE (NSLOT/64)        // 960 waves
#define CW ((GG+63)/64)         // 457 candidate bitmap words
#define CWP 512                 // padded word count (per-block scan width)
#define FS 64                   // u32 stride between flag entries (256 B line)
#define FP (256*FS)             // u32 offset between the two parity planes

// Agent-scope (device-coherent) accessors.
__device__ __forceinline__ unsigned int aload(const unsigned int* p) {
  return __hip_atomic_load(p, __ATOMIC_RELAXED, __HIP_MEMORY_SCOPE_AGENT);
}
__device__ __forceinline__ void astore(unsigned int* p, unsigned int v) {
  __hip_atomic_store(p, v, __ATOMIC_RELAXED, __HIP_MEMORY_SCOPE_AGENT);
}
__device__ __forceinline__ unsigned char aload8(const unsigned char* p) {
  return __hip_atomic_load(p, __ATOMIC_RELAXED, __HIP_MEMORY_SCOPE_AGENT);
}
__device__ __forceinline__ void astore8(unsigned char* p, unsigned char v) {
  __hip_atomic_store(p, v, __ATOMIC_RELAXED, __HIP_MEMORY_SCOPE_AGENT);
}

__device__ __forceinline__ int clampi(int v, int lo, int hi) {
  return v < lo ? lo : (v > hi ? hi : v);
}

// ---------------------------------------------------------------------------
// K0: zero the tag array + init both parity flag planes (ws is poisoned 0xAA).
// ---------------------------------------------------------------------------
__global__ __launch_bounds__(256) void k_init(unsigned int* __restrict__ flags,
                                              unsigned int* __restrict__ occ32)
{
  int idx = blockIdx.x * 256 + threadIdx.x;
  if (idx < (CW * 64 / 4)) occ32[idx] = 0u;          // 7312 words = 29248 tag bytes
  if (idx < 256) {
    unsigned v = (idx < NBLK) ? 0u : 0x7FFFFFFFu;    // pad blocks: epoch = +inf
    flags[idx * FS] = v;
    flags[FP + idx * FS] = v;
  }
}

// ---------------------------------------------------------------------------
// Flag-based grid barrier, RMW-free, with dead-count payload.
// Arrival: one agent store of (epoch<<9)|count to the block's own 256B line.
// Poll: wave 0 loads all 256 flag entries (4/lane), shfl-min over epochs.
// Parity planes alternate per step, so at break EVERY payload is exactly this
// step's (a block can't write this plane's next epoch without all blocks
// first passing the *other* plane's barrier). The poll registers therefore
// hold this step's dead counts -> lower-block prefix computed in-register.
// Safe: 240 blocks co-resident; __syncthreads drains vmcnt before the flag
// store, so all marks precede arrival (same argument as prior rounds).
// ---------------------------------------------------------------------------
__device__ __forceinline__ int barrier_ps(unsigned int* flagbase, int epoch,
                                          int myblk, int* psB, const int* wcnt)
{
  __syncthreads();
  if (threadIdx.x == 0) {
    int c = wcnt[0] + wcnt[1] + wcnt[2] + wcnt[3];
    astore(&flagbase[myblk * FS], ((unsigned)epoch << 9) | (unsigned)c);
  }
  if (threadIdx.x < 64) {
    const int lane = threadIdx.x;
    unsigned v0, v1, v2, v3;
    for (;;) {
      v0 = aload(&flagbase[(lane      ) * FS]);
      v1 = aload(&flagbase[(lane +  64) * FS]);
      v2 = aload(&flagbase[(lane + 128) * FS]);
      v3 = aload(&flagbase[(lane + 192) * FS]);
      unsigned m0 = v0 >> 9, m1 = v1 >> 9, m2 = v2 >> 9, m3 = v3 >> 9;
      unsigned mn = m0 < m1 ? m0 : m1;
      unsigned mn2 = m2 < m3 ? m2 : m3;
      mn = mn < mn2 ? mn : mn2;
      for (int o = 32; o > 0; o >>= 1) {
        unsigned t = (unsigned)__shfl_xor((int)mn, o, 64);
        mn = mn < t ? mn : t;
      }
      if ((int)mn >= epoch) break;
      __builtin_amdgcn_s_sleep(1);
    }
    int acc = 0;
    if (lane       < myblk) acc += (int)(v0 & 511u);
    if (lane +  64 < myblk) acc += (int)(v1 & 511u);
    if (lane + 128 < myblk) acc += (int)(v2 & 511u);
    if (lane + 192 < myblk) acc += (int)(v3 & 511u);
    for (int o = 32; o > 0; o >>= 1) acc += __shfl_xor(acc, o, 64);
    if (lane == 0) *psB = acc;
  }
  __syncthreads();
  return *psB;
}

// ---------------------------------------------------------------------------
// Bilinear footprint at (xs,ys). Identical float ops to the verified kernels.
// ---------------------------------------------------------------------------
struct Bil {
  int x0i, x1i, y0i, y1i;
  int i00, i01, i10, i11;
  float w00, w01, w10, w11;
};

__device__ __forceinline__ Bil mkbil(float xs, float ys) {
#pragma clang fp contract(off)
  float x0 = floorf(xs), y0 = floorf(ys);
  float wx1 = xs - x0, wx0 = 1.0f - wx1;
  float wy1 = ys - y0, wy0 = 1.0f - wy1;
  Bil b;
  b.x0i = clampi((int)x0, 0, WW - 1);
  b.x1i = b.x0i + 1 > WW - 1 ? WW - 1 : b.x0i + 1;
  b.y0i = clampi((int)y0, 0, HH - 1);
  b.y1i = b.y0i + 1 > HH - 1 ? HH - 1 : b.y0i + 1;
  b.i00 = b.y0i * WW + b.x0i; b.i01 = b.y0i * WW + b.x1i;
  b.i10 = b.y1i * WW + b.x0i; b.i11 = b.y1i * WW + b.x1i;
  b.w00 = wy0 * wx0; b.w01 = wy0 * wx1;
  b.w10 = wy1 * wx0; b.w11 = wy1 * wx1;
  return b;
}

// Fwd-bwd consistency bit from pre-gathered backward-flow corner values.
__device__ __forceinline__ float prune_val(float fx, float fy,
    float c00a, float c01a, float c10a, float c11a,
    float c00b, float c01b, float c10b, float c11b, const Bil& t)
{
#pragma clang fp contract(off)
  float bw0 = ((c00a * t.w00 + c01a * t.w01) + c10a * t.w10) + c11a * t.w11;
  float bw1 = ((c00b * t.w00 + c01b * t.w01) + c10b * t.w10) + c11b * t.w11;
  float t0 = fx + bw0, t1 = fy + bw1;
  float diff = sqrtf(t0 * t0 + t1 * t1);
  float magf = sqrtf(fx * fx + fy * fy);
  float magb = sqrtf(bw0 * bw0 + bw1 * bw1);
  float mag = 0.5f * (magf + magb);
  return (diff <= 0.01f * mag + 0.1f) ? 1.0f : 0.0f;
}

// ---------------------------------------------------------------------------
// K1: persistent scan, ONE grid barrier per step.
//   A(s):  prune-decide transition s (pure VALU for pipelined lanes; born
//          lanes run a short dependent-gather path); survivors mark occ with
//          step-tag bytes (plain stores, no RMW, no zeroing ever) and issue
//          the 8 f(s+1) tap loads; per-wave dead counts -> LDS  -> BARRIER
//   CD(s): advect via f(s+1) (drained by barrier), issue 32 b(s+1) loads
//          (soak under the rest of CD); every block rebuilds the free-cand
//          bitmap from the 29 KB tag array (coalesced byte loads + ballots);
//          popcount-prefix scan; births by rank (lower-block dead counts come
//          from the barrier flag payloads — no global wtot array at all).
// Stable order = word asc, bit asc = index asc (matches reference argsort).
// ---------------------------------------------------------------------------
__global__ __launch_bounds__(256, 1) void k_steps(
    const float* __restrict__ ff, const float* __restrict__ fbk,
    float* __restrict__ X, float* __restrict__ Y, float* __restrict__ Start,
    unsigned char* __restrict__ occ, unsigned int* __restrict__ flags)
{
#pragma clang fp contract(off)
  const int tid = blockIdx.x * 256 + threadIdx.x;   // slot id
  const int lane = tid & 63;
  const int wv = threadIdx.x >> 6;                   // wave-in-block 0..3
  const unsigned long long ltmask = (1ull << lane) - 1ull;

  __shared__ unsigned long long wds[CWP];   // free-candidate bitmap (4 KB)
  __shared__ unsigned int pref[CWP];        // inclusive popcount prefix (2 KB)
  __shared__ int wsum[4];                   // scan partials
  __shared__ int wcnt[4];                   // per-wave dead counts
  __shared__ int psB;                       // lower-block dead total

  // Slot state. mode: 0 dead, 1 pipelined (pf/pb/pxt valid), 2 fresh at
  // integer position (pf0/pf4 in flight).
  float x = 0.f, y = 0.f, st = -1.f;
  int mode = 0;
  float pf0 = 0.f, pf1 = 0.f, pf2 = 0.f, pf3 = 0.f;   // f0 at taps 00,01,10,11
  float pf4 = 0.f, pf5 = 0.f, pf6 = 0.f, pf7 = 0.f;   // f1 at taps 00,01,10,11
  float pb[32];                                        // b corner values, 8/tap
  float pxt = 0.f, pyt = 0.f;                          // advected candidate
  bool  pmarg = false;

  if (tid < GG) {
    int ii = tid / GXC, jj = tid - ii * GXC;
    int ix = MARGIN + STEP * jj, iy = MARGIN + STEP * ii;
    x = (float)ix; y = (float)iy;
    st = 0.f; mode = 2;
    int p = iy * WW + ix;
    pf0 = ff[p];            // f0[s=0] at the integer start position
    pf4 = ff[HW + p];       // f1[s=0]
  }
  X[tid] = x; Y[tid] = y;   // row 0

// Issue the 32 b-corner loads for tap tt (consumed next iteration's A).
#define ISSUE_TAP(tt, TXI, TYI, FX, FY) do { \
    Bil Bt = mkbil((float)P.TXI + (FX), (float)P.TYI + (FY)); \
    pb[(tt)*8+0] = b0n[Bt.i00]; pb[(tt)*8+1] = b0n[Bt.i01]; \
    pb[(tt)*8+2] = b0n[Bt.i10]; pb[(tt)*8+3] = b0n[Bt.i11]; \
    pb[(tt)*8+4] = b1n[Bt.i00]; pb[(tt)*8+5] = b1n[Bt.i01]; \
    pb[(tt)*8+6] = b1n[Bt.i10]; pb[(tt)*8+7] = b1n[Bt.i11]; \
  } while (0)

// Recompute the identical footprint and fold pre-loaded values into the bit.
#define PRUNE_TAP(tt, TXI, TYI, FX, FY, OUT) do { \
    Bil Bt = mkbil((float)P.TXI + (FX), (float)P.TYI + (FY)); \
    OUT = prune_val((FX), (FY), \
                    pb[(tt)*8+0], pb[(tt)*8+1], pb[(tt)*8+2], pb[(tt)*8+3], \
                    pb[(tt)*8+4], pb[(tt)*8+5], pb[(tt)*8+6], pb[(tt)*8+7], Bt); \
  } while (0)

  for (int s = 0; s < SS - 1; ++s) {
    const float* b0  = fbk + (size_t)s * 2 * HW;       // this step's bwd flow
    const float* b1  = b0 + HW;
    const float* f0n = ff + (size_t)(s + 1) * 2 * HW;  // NEXT step's fwd flow
    const float* f1n = f0n + HW;
    const unsigned char tag = (unsigned char)(s + 1);

    // ---- Phase A: prune decision + occ tag marks + dead counts ------------
    bool moved = false;
    if (mode == 1) {
      Bil P = mkbil(x, y);
      float o0, o1, o2, o3;
      PRUNE_TAP(0, x0i, y0i, pf0, pf4, o0);
      PRUNE_TAP(1, x1i, y0i, pf1, pf5, o1);
      PRUNE_TAP(2, x0i, y1i, pf2, pf6, o2);
      PRUNE_TAP(3, x1i, y1i, pf3, pf7, o3);
      float fbv = ((o0 * P.w00 + o1 * P.w01) + o2 * P.w10) + o3 * P.w11;
      if (pmarg && fbv > 0.5f) {
        x = pxt; y = pyt;
        Bil Pn = mkbil(x, y);                 // prefetch f for step s+1
        pf0 = f0n[Pn.i00]; pf1 = f0n[Pn.i01]; pf2 = f0n[Pn.i10]; pf3 = f0n[Pn.i11];
        pf4 = f1n[Pn.i00]; pf5 = f1n[Pn.i01]; pf6 = f1n[Pn.i10]; pf7 = f1n[Pn.i11];
        moved = true;
      } else { st = -1.f; x = 0.f; y = 0.f; mode = 0; }
    } else if (mode == 2) {
      // Integer position: weights degenerate exactly (w00=1, rest=0) ->
      // u = f0[p], v = f1[p], fb = o00. Bit-identical to the generic path.
      float u = pf0, v = pf4;
      float xt = x + u, yt = y + v;
      bool marg = (xt > (float)MARGIN) && (yt > (float)MARGIN) &&
                  (xt < (float)(WW - MARGIN)) && (yt < (float)(HH - MARGIN));
      Bil Bt = mkbil(xt, yt);
      float o00 = prune_val(u, v,
                            b0[Bt.i00], b0[Bt.i01], b0[Bt.i10], b0[Bt.i11],
                            b1[Bt.i00], b1[Bt.i01], b1[Bt.i10], b1[Bt.i11], Bt);
      if (marg && o00 > 0.5f) {
        x = xt; y = yt; mode = 1;
        Bil Pn = mkbil(x, y);                 // prefetch f for step s+1
        pf0 = f0n[Pn.i00]; pf1 = f0n[Pn.i01]; pf2 = f0n[Pn.i10]; pf3 = f0n[Pn.i11];
        pf4 = f1n[Pn.i00]; pf5 = f1n[Pn.i01]; pf6 = f1n[Pn.i10]; pf7 = f1n[Pn.i11];
        moved = true;
      } else { st = -1.f; x = 0.f; y = 0.f; mode = 0; }
    }
    if (moved) {
      int oy = (int)y, ox = (int)x;   // trunc == floor (positive)
      int i0 = ((oy - (MARGIN + 2) + 4099) >> 2) - 1024;  // ceil((oy-12)/4)
      int i1 = ((oy - (MARGIN - 2) + 4096) >> 2) - 1024;  // floor((oy-8)/4)
      int j0 = ((ox - (MARGIN + 2) + 4099) >> 2) - 1024;
      int j1 = ((ox - (MARGIN - 2) + 4096) >> 2) - 1024;
      if (i0 < 0) i0 = 0; if (i1 > GYC - 1) i1 = GYC - 1;
      if (j0 < 0) j0 = 0; if (j1 > GXC - 1) j1 = GXC - 1;
      for (int i = i0; i <= i1; ++i)
        for (int j = j0; j <= j1; ++j)
          astore8(&occ[i * GXC + j], tag);   // same-value stores: benign race
    }
    unsigned long long smask = __ballot(st < 0.0f);
    if (lane == 0) wcnt[wv] = (int)__popcll(smask);

    int ps = barrier_ps(flags + (s & 1) * FP, s + 1, blockIdx.x, &psB, wcnt);

    // ---- Phase CD: pipeline issue, local bitmap rebuild, births -----------
    if (mode == 1 && s < SS - 2) {
      Bil P = mkbil(x, y);
      float u_ = ((pf0 * P.w00 + pf1 * P.w01) + pf2 * P.w10) + pf3 * P.w11;
      float v_ = ((pf4 * P.w00 + pf5 * P.w01) + pf6 * P.w10) + pf7 * P.w11;
      pxt = x + u_; pyt = y + v_;
      pmarg = (pxt > (float)MARGIN) && (pyt > (float)MARGIN) &&
              (pxt < (float)(WW - MARGIN)) && (pyt < (float)(HH - MARGIN));
      const float* b0n = fbk + (size_t)(s + 1) * 2 * HW;
      const float* b1n = b0n + HW;
      ISSUE_TAP(0, x0i, y0i, pf0, pf4);
      ISSUE_TAP(1, x1i, y0i, pf1, pf5);
      ISSUE_TAP(2, x0i, y1i, pf2, pf6);
      ISSUE_TAP(3, x1i, y1i, pf3, pf7);
    }
    // Block-local free-candidate bitmap from the tag array (coalesced bytes).
    {
#pragma unroll 4
      for (int k = wv; k < CW; k += 4) {
        int g = k * 64 + lane;
        unsigned char tv = aload8(&occ[g]);     // occ padded to CW*64 bytes
        bool fr = (g < GG) && (tv != tag);
        unsigned long long cm = __ballot(fr);
        if (lane == 0) wds[k] = cm;
      }
    }
    __syncthreads();
    // Popcount prefix over the bitmap (shuffle scan, as verified).
    {
      int t = threadIdx.x;
      int e0 = 2 * t, e1 = 2 * t + 1;
      unsigned long long m0 = (e0 < CW) ? wds[e0] : 0ull;
      unsigned long long m1 = (e1 < CW) ? wds[e1] : 0ull;
      int p0 = __popcll(m0), p1 = __popcll(m1);
      int v = p0 + p1;
      for (int o = 1; o < 64; o <<= 1) {
        int uu = __shfl_up(v, o, 64);
        if (lane >= o) v += uu;
      }
      if (lane == 63) wsum[wv] = v;
      __syncthreads();
      int base = 0;
      for (int j2 = 0; j2 < wv; ++j2) base += wsum[j2];
      pref[e0] = (unsigned int)(base + v - p1);
      pref[e1] = (unsigned int)(base + v);
      __syncthreads();
    }
    int tc = (int)pref[CWP - 1];              // total free candidates

    // dead-slot rank: lower blocks (flag payloads) + lower waves + lower lanes
    int lower = 0;
    for (int j2 = 0; j2 < wv; ++j2) lower += wcnt[j2];

    if (st < 0.0f) {
      int r = ps + lower + (int)__popcll(smask & ltmask);
      if (r < tc) {                  // r < min(num_cand, num_free) <=> r < num_cand
        // word k containing rank r: largest k with pref[k-1] <= r
        int k = 0;
        for (int b = 256; b >= 1; b >>= 1) {
          int nk = k + b;
          if (nk <= CWP - 1 && (int)pref[nk - 1] <= r) k = nk;
        }
        int j = r - (k ? (int)pref[k - 1] : 0);
        unsigned long long m = wds[k];
        int lo = 0;                  // position of the (j+1)-th set bit
        for (int b = 32; b >= 1; b >>= 1) {
          int nb = lo + b;
          unsigned long long mask = (nb >= 64) ? ~0ull : ((1ull << nb) - 1ull);
          if (__popcll(m & mask) <= j) lo = nb;
        }
        int g = k * 64 + lo;
        int ii = g / GXC, jj = g - ii * GXC;
        int ix = MARGIN + STEP * jj, iy = MARGIN + STEP * ii;
        x = (float)ix; y = (float)iy;
        st = (float)(s + 1);
        mode = 2;
        int p = iy * WW + ix;
        pf0 = f0n[p];               // issue the born slot's f-loads now
        pf4 = f1n[p];
      }
    }
    X[(size_t)(s + 1) * NSLOT + tid] = x;
    Y[(size_t)(s + 1) * NSLOT + tid] = y;
    __syncthreads();   // protect wcnt (read above) from next A's writes
  }

#undef ISSUE_TAP
#undef PRUNE_TAP

  Start[tid] = st;
}

// ---------------------------------------------------------------------------
extern "C" void kernel_launch(void* const* d_in, const int* in_sizes, int n_in,
                              void* d_out, int out_size, void* d_ws, size_t ws_size,
                              hipStream_t stream) {
  const float* ff  = (const float*)d_in[0];   // (1,S,2,H,W)
  const float* fbk = (const float*)d_in[1];

  float* X     = (float*)d_out;                       // (S, N)
  float* Y     = X + (size_t)SS * NSLOT;              // (S, N)
  float* Start = Y + (size_t)SS * NSLOT;              // (N,)

  unsigned int*  flags = (unsigned int*)d_ws;                 // 2 parity planes, 128 KB
  unsigned char* occ   = (unsigned char*)(flags + 2 * FP);    // CW*64 tag bytes

  k_init<<<29, 256, 0, stream>>>(flags, (unsigned int*)occ);

  k_steps<<<NBLK, 256, 0, stream>>>(ff, fbk, X, Y, Start, occ, flags);
}

// Round 4
// 622.720 us; speedup vs baseline: 2.2085x; 2.2085x over previous
//
#include <hip/hip_runtime.h>
#include <cstdint>

// Problem constants (fixed by setup_inputs: H=480, W=1024, S=32, margin=10, step=4)
#define HH 480
#define WW 1024
#define SS 32
#define HW (HH*WW)              // 491520
#define MARGIN 10
#define STEP 4
#define GYC 116                 // len(arange(10, 471, 4))
#define GXC 252                 // len(arange(10, 1015, 4))
#define GG (GYC*GXC)            // 29232 grid candidates
#define NSLOT (2*HH*WW/(STEP*STEP))  // 61440 trajectory slots
#define NBLK (NSLOT/256)        // 240 blocks -> co-resident on 256 CUs
#define NWAVE (NSLOT/64)        // 960 waves
#define CW ((GG+63)/64)         // 457 candidate bitmap words
#define CWP 512                 // padded word count (per-block scan width)
#define FS 64                   // u32 stride between flag entries (256 B line)
#define FP (256*FS)             // u32 offset between the two parity planes

// Agent-scope (device-coherent) accessors.
__device__ __forceinline__ unsigned int aload(const unsigned int* p) {
  return __hip_atomic_load(p, __ATOMIC_RELAXED, __HIP_MEMORY_SCOPE_AGENT);
}
__device__ __forceinline__ void astore(unsigned int* p, unsigned int v) {
  __hip_atomic_store(p, v, __ATOMIC_RELAXED, __HIP_MEMORY_SCOPE_AGENT);
}
__device__ __forceinline__ void astore8(unsigned char* p, unsigned char v) {
  __hip_atomic_store(p, v, __ATOMIC_RELAXED, __HIP_MEMORY_SCOPE_AGENT);
}

__device__ __forceinline__ int clampi(int v, int lo, int hi) {
  return v < lo ? lo : (v > hi ? hi : v);
}

// ---------------------------------------------------------------------------
// K0: zero the tag array + init both parity flag planes (ws is poisoned 0xAA).
// ---------------------------------------------------------------------------
__global__ __launch_bounds__(256) void k_init(unsigned int* __restrict__ flags,
                                              unsigned int* __restrict__ occ32)
{
  int idx = blockIdx.x * 256 + threadIdx.x;
  if (idx < (CW * 16)) occ32[idx] = 0u;              // 7312 words = 29248 tag bytes
  if (idx < 256) {
    unsigned v = (idx < NBLK) ? 0u : 0x7FFFFFFFu;    // pad blocks: epoch = +inf
    flags[idx * FS] = v;
    flags[FP + idx * FS] = v;
  }
}

// ---------------------------------------------------------------------------
// Flag-based grid barrier, RMW-free, with dead-count payload.
// Arrival: one agent store of (epoch<<9)|count to the block's own 256B line.
// Poll: wave 0 loads all 256 flag entries (4/lane), shfl-min over epochs.
// Parity planes alternate per step, so at break EVERY payload is exactly this
// step's (a block can't write this plane's next epoch without all blocks
// first passing the *other* plane's barrier). The poll registers therefore
// hold this step's dead counts -> lower-block prefix computed in-register.
// Safe: 240 blocks co-resident; __syncthreads drains vmcnt before the flag
// store, so all marks precede arrival (same argument as prior rounds).
// ---------------------------------------------------------------------------
__device__ __forceinline__ int barrier_ps(unsigned int* flagbase, int epoch,
                                          int myblk, int* psB, const int* wcnt)
{
  __syncthreads();
  if (threadIdx.x == 0) {
    int c = wcnt[0] + wcnt[1] + wcnt[2] + wcnt[3];
    astore(&flagbase[myblk * FS], ((unsigned)epoch << 9) | (unsigned)c);
  }
  if (threadIdx.x < 64) {
    const int lane = threadIdx.x;
    unsigned v0, v1, v2, v3;
    for (;;) {
      v0 = aload(&flagbase[(lane      ) * FS]);
      v1 = aload(&flagbase[(lane +  64) * FS]);
      v2 = aload(&flagbase[(lane + 128) * FS]);
      v3 = aload(&flagbase[(lane + 192) * FS]);
      unsigned m0 = v0 >> 9, m1 = v1 >> 9, m2 = v2 >> 9, m3 = v3 >> 9;
      unsigned mn = m0 < m1 ? m0 : m1;
      unsigned mn2 = m2 < m3 ? m2 : m3;
      mn = mn < mn2 ? mn : mn2;
      for (int o = 32; o > 0; o >>= 1) {
        unsigned t = (unsigned)__shfl_xor((int)mn, o, 64);
        mn = mn < t ? mn : t;
      }
      if ((int)mn >= epoch) break;
      __builtin_amdgcn_s_sleep(1);
    }
    int acc = 0;
    if (lane       < myblk) acc += (int)(v0 & 511u);
    if (lane +  64 < myblk) acc += (int)(v1 & 511u);
    if (lane + 128 < myblk) acc += (int)(v2 & 511u);
    if (lane + 192 < myblk) acc += (int)(v3 & 511u);
    for (int o = 32; o > 0; o >>= 1) acc += __shfl_xor(acc, o, 64);
    if (lane == 0) *psB = acc;
  }
  __syncthreads();
  return *psB;
}

// ---------------------------------------------------------------------------
// Bilinear footprint at (xs,ys). Identical float ops to the verified kernels.
// ---------------------------------------------------------------------------
struct Bil {
  int x0i, x1i, y0i, y1i;
  int i00, i01, i10, i11;
  float w00, w01, w10, w11;
};

__device__ __forceinline__ Bil mkbil(float xs, float ys) {
#pragma clang fp contract(off)
  float x0 = floorf(xs), y0 = floorf(ys);
  float wx1 = xs - x0, wx0 = 1.0f - wx1;
  float wy1 = ys - y0, wy0 = 1.0f - wy1;
  Bil b;
  b.x0i = clampi((int)x0, 0, WW - 1);
  b.x1i = b.x0i + 1 > WW - 1 ? WW - 1 : b.x0i + 1;
  b.y0i = clampi((int)y0, 0, HH - 1);
  b.y1i = b.y0i + 1 > HH - 1 ? HH - 1 : b.y0i + 1;
  b.i00 = b.y0i * WW + b.x0i; b.i01 = b.y0i * WW + b.x1i;
  b.i10 = b.y1i * WW + b.x0i; b.i11 = b.y1i * WW + b.x1i;
  b.w00 = wy0 * wx0; b.w01 = wy0 * wx1;
  b.w10 = wy1 * wx0; b.w11 = wy1 * wx1;
  return b;
}

// Fwd-bwd consistency bit from pre-gathered backward-flow corner values.
__device__ __forceinline__ float prune_val(float fx, float fy,
    float c00a, float c01a, float c10a, float c11a,
    float c00b, float c01b, float c10b, float c11b, const Bil& t)
{
#pragma clang fp contract(off)
  float bw0 = ((c00a * t.w00 + c01a * t.w01) + c10a * t.w10) + c11a * t.w11;
  float bw1 = ((c00b * t.w00 + c01b * t.w01) + c10b * t.w10) + c11b * t.w11;
  float t0 = fx + bw0, t1 = fy + bw1;
  float diff = sqrtf(t0 * t0 + t1 * t1);
  float magf = sqrtf(fx * fx + fy * fy);
  float magb = sqrtf(bw0 * bw0 + bw1 * bw1);
  float mag = 0.5f * (magf + magb);
  return (diff <= 0.01f * mag + 0.1f) ? 1.0f : 0.0f;
}

// ---------------------------------------------------------------------------
// K1: persistent scan, ONE grid barrier per step.
//   A(s):  prune-decide transition s (pure VALU for pipelined lanes; born
//          lanes run a short dependent-gather path); survivors mark occ with
//          step-tag bytes (plain stores, no RMW, no zeroing ever) and issue
//          the 8 f(s+1) tap loads; per-wave dead counts -> LDS  -> BARRIER
//   CD(s): rebuild the free-candidate bitmap from the 29 KB tag array with
//          29 INDEPENDENT coalesced u32 agent loads/thread + SWAR byte-compare
//          -> nibble LDS array -> u64 words (round 3's ballot-per-word chain
//          was ~29 serialized L3 latencies — the regression); pipelined
//          advect + issue 32 b(s+1) loads overlap the occ-load latency;
//          popcount-prefix scan; births by rank (lower-block dead counts from
//          the barrier flag payloads — no global wtot array, no 2nd barrier).
// Stable order = word asc, bit asc = index asc (matches reference argsort).
// ---------------------------------------------------------------------------
__global__ __launch_bounds__(256, 1) void k_steps(
    const float* __restrict__ ff, const float* __restrict__ fbk,
    float* __restrict__ X, float* __restrict__ Y, float* __restrict__ Start,
    unsigned char* __restrict__ occ, unsigned int* __restrict__ flags)
{
#pragma clang fp contract(off)
  const int tid = blockIdx.x * 256 + threadIdx.x;   // slot id
  const int lane = tid & 63;
  const int wv = threadIdx.x >> 6;                   // wave-in-block 0..3
  const unsigned long long ltmask = (1ull << lane) - 1ull;

  __shared__ unsigned long long wds[CWP];   // free-candidate bitmap (4 KB)
  __shared__ unsigned int pref[CWP];        // inclusive popcount prefix (2 KB)
  __shared__ unsigned int nibs32[CW * 4];   // nibble staging (7312 B)
  __shared__ int wsum[4];                   // scan partials
  __shared__ int wcnt[4];                   // per-wave dead counts
  __shared__ int psB;                       // lower-block dead total

  // Slot state. mode: 0 dead, 1 pipelined (pf/pb/pxt valid), 2 fresh at
  // integer position (pf0/pf4 in flight).
  float x = 0.f, y = 0.f, st = -1.f;
  int mode = 0;
  float pf0 = 0.f, pf1 = 0.f, pf2 = 0.f, pf3 = 0.f;   // f0 at taps 00,01,10,11
  float pf4 = 0.f, pf5 = 0.f, pf6 = 0.f, pf7 = 0.f;   // f1 at taps 00,01,10,11
  float pb[32];                                        // b corner values, 8/tap
  float pxt = 0.f, pyt = 0.f;                          // advected candidate
  bool  pmarg = false;

  if (tid < GG) {
    int ii = tid / GXC, jj = tid - ii * GXC;
    int ix = MARGIN + STEP * jj, iy = MARGIN + STEP * ii;
    x = (float)ix; y = (float)iy;
    st = 0.f; mode = 2;
    int p = iy * WW + ix;
    pf0 = ff[p];            // f0[s=0] at the integer start position
    pf4 = ff[HW + p];       // f1[s=0]
  }
  X[tid] = x; Y[tid] = y;   // row 0

// Issue the 32 b-corner loads for tap tt (consumed next iteration's A).
#define ISSUE_TAP(tt, TXI, TYI, FX, FY) do { \
    Bil Bt = mkbil((float)P.TXI + (FX), (float)P.TYI + (FY)); \
    pb[(tt)*8+0] = b0n[Bt.i00]; pb[(tt)*8+1] = b0n[Bt.i01]; \
    pb[(tt)*8+2] = b0n[Bt.i10]; pb[(tt)*8+3] = b0n[Bt.i11]; \
    pb[(tt)*8+4] = b1n[Bt.i00]; pb[(tt)*8+5] = b1n[Bt.i01]; \
    pb[(tt)*8+6] = b1n[Bt.i10]; pb[(tt)*8+7] = b1n[Bt.i11]; \
  } while (0)

// Recompute the identical footprint and fold pre-loaded values into the bit.
#define PRUNE_TAP(tt, TXI, TYI, FX, FY, OUT) do { \
    Bil Bt = mkbil((float)P.TXI + (FX), (float)P.TYI + (FY)); \
    OUT = prune_val((FX), (FY), \
                    pb[(tt)*8+0], pb[(tt)*8+1], pb[(tt)*8+2], pb[(tt)*8+3], \
                    pb[(tt)*8+4], pb[(tt)*8+5], pb[(tt)*8+6], pb[(tt)*8+7], Bt); \
  } while (0)

  for (int s = 0; s < SS - 1; ++s) {
    const float* b0  = fbk + (size_t)s * 2 * HW;       // this step's bwd flow
    const float* b1  = b0 + HW;
    const float* f0n = ff + (size_t)(s + 1) * 2 * HW;  // NEXT step's fwd flow
    const float* f1n = f0n + HW;
    const unsigned char tag = (unsigned char)(s + 1);

    // ---- Phase A: prune decision + occ tag marks + dead counts ------------
    bool moved = false;
    if (mode == 1) {
      Bil P = mkbil(x, y);
      float o0, o1, o2, o3;
      PRUNE_TAP(0, x0i, y0i, pf0, pf4, o0);
      PRUNE_TAP(1, x1i, y0i, pf1, pf5, o1);
      PRUNE_TAP(2, x0i, y1i, pf2, pf6, o2);
      PRUNE_TAP(3, x1i, y1i, pf3, pf7, o3);
      float fbv = ((o0 * P.w00 + o1 * P.w01) + o2 * P.w10) + o3 * P.w11;
      if (pmarg && fbv > 0.5f) {
        x = pxt; y = pyt;
        Bil Pn = mkbil(x, y);                 // prefetch f for step s+1
        pf0 = f0n[Pn.i00]; pf1 = f0n[Pn.i01]; pf2 = f0n[Pn.i10]; pf3 = f0n[Pn.i11];
        pf4 = f1n[Pn.i00]; pf5 = f1n[Pn.i01]; pf6 = f1n[Pn.i10]; pf7 = f1n[Pn.i11];
        moved = true;
      } else { st = -1.f; x = 0.f; y = 0.f; mode = 0; }
    } else if (mode == 2) {
      // Integer position: weights degenerate exactly (w00=1, rest=0) ->
      // u = f0[p], v = f1[p], fb = o00. Bit-identical to the generic path.
      float u = pf0, v = pf4;
      float xt = x + u, yt = y + v;
      bool marg = (xt > (float)MARGIN) && (yt > (float)MARGIN) &&
                  (xt < (float)(WW - MARGIN)) && (yt < (float)(HH - MARGIN));
      Bil Bt = mkbil(xt, yt);
      float o00 = prune_val(u, v,
                            b0[Bt.i00], b0[Bt.i01], b0[Bt.i10], b0[Bt.i11],
                            b1[Bt.i00], b1[Bt.i01], b1[Bt.i10], b1[Bt.i11], Bt);
      if (marg && o00 > 0.5f) {
        x = xt; y = yt; mode = 1;
        Bil Pn = mkbil(x, y);                 // prefetch f for step s+1
        pf0 = f0n[Pn.i00]; pf1 = f0n[Pn.i01]; pf2 = f0n[Pn.i10]; pf3 = f0n[Pn.i11];
        pf4 = f1n[Pn.i00]; pf5 = f1n[Pn.i01]; pf6 = f1n[Pn.i10]; pf7 = f1n[Pn.i11];
        moved = true;
      } else { st = -1.f; x = 0.f; y = 0.f; mode = 0; }
    }
    if (moved) {
      int oy = (int)y, ox = (int)x;   // trunc == floor (positive)
      int i0 = ((oy - (MARGIN + 2) + 4099) >> 2) - 1024;  // ceil((oy-12)/4)
      int i1 = ((oy - (MARGIN - 2) + 4096) >> 2) - 1024;  // floor((oy-8)/4)
      int j0 = ((ox - (MARGIN + 2) + 4099) >> 2) - 1024;
      int j1 = ((ox - (MARGIN - 2) + 4096) >> 2) - 1024;
      if (i0 < 0) i0 = 0; if (i1 > GYC - 1) i1 = GYC - 1;
      if (j0 < 0) j0 = 0; if (j1 > GXC - 1) j1 = GXC - 1;
      for (int i = i0; i <= i1; ++i)
        for (int j = j0; j <= j1; ++j)
          astore8(&occ[i * GXC + j], tag);   // same-value stores: benign race
    }
    unsigned long long smask = __ballot(st < 0.0f);
    if (lane == 0) wcnt[wv] = (int)__popcll(smask);

    int ps = barrier_ps(flags + (s & 1) * FP, s + 1, blockIdx.x, &psB, wcnt);

    // ---- Phase CD: bitmap rebuild (SWAR), pipeline issue, births ----------
    // Pass 1: 29 independent coalesced agent u32 loads/thread; byte-compare
    // against tag (SWAR) -> 4 free-bits -> one nibble-byte per u32 into LDS.
    {
      const unsigned int* occ32 = (const unsigned int*)occ;
      const unsigned int tagrep = 0x01010101u * (unsigned)tag;
      unsigned char* nb = (unsigned char*)nibs32;
      int t = threadIdx.x;
#pragma unroll
      for (int r = 0; r < 29; ++r) {
        int j = t + 256 * r;
        if (j < CW * 16) {
          unsigned v = aload(&occ32[j]);
          unsigned xx = v ^ tagrep;                      // byte==tag -> 0x00
          unsigned t1 = (xx & 0x7F7F7F7Fu) + 0x7F7F7F7Fu;
          unsigned nz = ((t1 | xx) >> 7) & 0x01010101u;  // byte!=tag -> 1 (free)
          unsigned nib = ((nz * 0x01020408u) >> 24) & 0xFu;  // cell-ascending
          nb[j] = (unsigned char)nib;
        }
      }
    }
    // Pipelined advect + b-load issue overlaps the occ-load/SWAR latency.
    if (mode == 1 && s < SS - 2) {
      Bil P = mkbil(x, y);
      float u_ = ((pf0 * P.w00 + pf1 * P.w01) + pf2 * P.w10) + pf3 * P.w11;
      float v_ = ((pf4 * P.w00 + pf5 * P.w01) + pf6 * P.w10) + pf7 * P.w11;
      pxt = x + u_; pyt = y + v_;
      pmarg = (pxt > (float)MARGIN) && (pyt > (float)MARGIN) &&
              (pxt < (float)(WW - MARGIN)) && (pyt < (float)(HH - MARGIN));
      const float* b0n = fbk + (size_t)(s + 1) * 2 * HW;
      const float* b1n = b0n + HW;
      ISSUE_TAP(0, x0i, y0i, pf0, pf4);
      ISSUE_TAP(1, x1i, y0i, pf1, pf5);
      ISSUE_TAP(2, x0i, y1i, pf2, pf6);
      ISSUE_TAP(3, x1i, y1i, pf3, pf7);
    }
    __syncthreads();
    // Pass 2: assemble u64 words from 16 nibble-bytes; mask tail; zero pads.
    for (int k = threadIdx.x; k < CWP; k += 256) {
      unsigned long long wdv = 0ull;
      if (k < CW) {
        unsigned v0 = nibs32[4 * k + 0], v1 = nibs32[4 * k + 1];
        unsigned v2 = nibs32[4 * k + 2], v3 = nibs32[4 * k + 3];
        unsigned q0 = ((v0 | (v0 >> 4)) & 0x00FF00FFu); q0 = (q0 | (q0 >> 8)) & 0xFFFFu;
        unsigned q1 = ((v1 | (v1 >> 4)) & 0x00FF00FFu); q1 = (q1 | (q1 >> 8)) & 0xFFFFu;
        unsigned q2 = ((v2 | (v2 >> 4)) & 0x00FF00FFu); q2 = (q2 | (q2 >> 8)) & 0xFFFFu;
        unsigned q3 = ((v3 | (v3 >> 4)) & 0x00FF00FFu); q3 = (q3 | (q3 >> 8)) & 0xFFFFu;
        wdv = (unsigned long long)q0 | ((unsigned long long)q1 << 16)
            | ((unsigned long long)q2 << 32) | ((unsigned long long)q3 << 48);
        if (k == CW - 1) wdv &= (1ull << 48) - 1ull;   // cells >= GG are pad
      }
      wds[k] = wdv;
    }
    __syncthreads();
    // Popcount prefix over the bitmap (shuffle scan, as verified).
    {
      int t = threadIdx.x;
      int e0 = 2 * t, e1 = 2 * t + 1;
      unsigned long long m0 = wds[e0];
      unsigned long long m1 = wds[e1];
      int p0 = __popcll(m0), p1 = __popcll(m1);
      int v = p0 + p1;
      for (int o = 1; o < 64; o <<= 1) {
        int uu = __shfl_up(v, o, 64);
        if (lane >= o) v += uu;
      }
      if (lane == 63) wsum[wv] = v;
      __syncthreads();
      int base = 0;
      for (int j2 = 0; j2 < wv; ++j2) base += wsum[j2];
      pref[e0] = (unsigned int)(base + v - p1);
      pref[e1] = (unsigned int)(base + v);
      __syncthreads();
    }
    int tc = (int)pref[CWP - 1];              // total free candidates

    // dead-slot rank: lower blocks (flag payloads) + lower waves + lower lanes
    int lower = 0;
    for (int j2 = 0; j2 < wv; ++j2) lower += wcnt[j2];

    if (st < 0.0f) {
      int r = ps + lower + (int)__popcll(smask & ltmask);
      if (r < tc) {                  // r < min(num_cand, num_free) <=> r < num_cand
        // word k containing rank r: largest k with pref[k-1] <= r
        int k = 0;
        for (int b = 256; b >= 1; b >>= 1) {
          int nk = k + b;
          if (nk <= CWP - 1 && (int)pref[nk - 1] <= r) k = nk;
        }
        int j = r - (k ? (int)pref[k - 1] : 0);
        unsigned long long m = wds[k];
        int lo = 0;                  // position of the (j+1)-th set bit
        for (int b = 32; b >= 1; b >>= 1) {
          int nb = lo + b;
          unsigned long long mask = (nb >= 64) ? ~0ull : ((1ull << nb) - 1ull);
          if (__popcll(m & mask) <= j) lo = nb;
        }
        int g = k * 64 + lo;
        int ii = g / GXC, jj = g - ii * GXC;
        int ix = MARGIN + STEP * jj, iy = MARGIN + STEP * ii;
        x = (float)ix; y = (float)iy;
        st = (float)(s + 1);
        mode = 2;
        int p = iy * WW + ix;
        pf0 = f0n[p];               // issue the born slot's f-loads now
        pf4 = f1n[p];
      }
    }
    X[(size_t)(s + 1) * NSLOT + tid] = x;
    Y[(size_t)(s + 1) * NSLOT + tid] = y;
    __syncthreads();   // protect wcnt (read above) from next A's writes
  }

#undef ISSUE_TAP
#undef PRUNE_TAP

  Start[tid] = st;
}

// ---------------------------------------------------------------------------
extern "C" void kernel_launch(void* const* d_in, const int* in_sizes, int n_in,
                              void* d_out, int out_size, void* d_ws, size_t ws_size,
                              hipStream_t stream) {
  const float* ff  = (const float*)d_in[0];   // (1,S,2,H,W)
  const float* fbk = (const float*)d_in[1];

  float* X     = (float*)d_out;                       // (S, N)
  float* Y     = X + (size_t)SS * NSLOT;              // (S, N)
  float* Start = Y + (size_t)SS * NSLOT;              // (N,)

  unsigned int*  flags = (unsigned int*)d_ws;                 // 2 parity planes, 128 KB
  unsigned char* occ   = (unsigned char*)(flags + 2 * FP);    // CW*64 tag bytes

  k_init<<<29, 256, 0, stream>>>(flags, (unsigned int*)occ);

  k_steps<<<NBLK, 256, 0, stream>>>(ff, fbk, X, Y, Start, occ, flags);
}

// Round 5
// 431.586 us; speedup vs baseline: 3.1866x; 1.4429x over previous
//
#include <hip/hip_runtime.h>
#include <cstdint>

// Problem constants (fixed by setup_inputs: H=480, W=1024, S=32, margin=10, step=4)
#define HH 480
#define WW 1024
#define SS 32
#define HW (HH*WW)              // 491520
#define MARGIN 10
#define STEP 4
#define GYC 116                 // len(arange(10, 471, 4))
#define GXC 252                 // len(arange(10, 1015, 4))
#define GG (GYC*GXC)            // 29232 grid candidates (= 8*3654 exactly)
#define NSLOT (2*HH*WW/(STEP*STEP))  // 61440 trajectory slots
#define NBLK (NSLOT/256)        // 240 blocks -> co-resident on 256 CUs
#define NWAVE (NSLOT/64)        // 960 waves
#define CW ((GG+63)/64)         // 457 candidate bitmap words
#define CWP 512                 // padded word count (per-block scan width)
#define OCCB (CW*64)            // 29248 bytes per occupancy plane
#define FS 64                   // u32 stride between flag entries (256 B line)
#define FP (256*FS)             // u32 offset between the two parity planes

// Agent-scope (device-coherent) accessors.
__device__ __forceinline__ unsigned int aload(const unsigned int* p) {
  return __hip_atomic_load(p, __ATOMIC_RELAXED, __HIP_MEMORY_SCOPE_AGENT);
}
__device__ __forceinline__ void astore(unsigned int* p, unsigned int v) {
  __hip_atomic_store(p, v, __ATOMIC_RELAXED, __HIP_MEMORY_SCOPE_AGENT);
}
__device__ __forceinline__ unsigned long long aload64(const unsigned long long* p) {
  return __hip_atomic_load(p, __ATOMIC_RELAXED, __HIP_MEMORY_SCOPE_AGENT);
}
__device__ __forceinline__ void astore64(unsigned long long* p, unsigned long long v) {
  __hip_atomic_store(p, v, __ATOMIC_RELAXED, __HIP_MEMORY_SCOPE_AGENT);
}
__device__ __forceinline__ void astore8(unsigned char* p, unsigned char v) {
  __hip_atomic_store(p, v, __ATOMIC_RELAXED, __HIP_MEMORY_SCOPE_AGENT);
}

__device__ __forceinline__ int clampi(int v, int lo, int hi) {
  return v < lo ? lo : (v > hi ? hi : v);
}

// ---------------------------------------------------------------------------
// K0: zero BOTH occupancy tag planes + init both parity flag planes.
// ---------------------------------------------------------------------------
__global__ __launch_bounds__(256) void k_init(unsigned int* __restrict__ flags,
                                              unsigned int* __restrict__ occ32)
{
  int idx = blockIdx.x * 256 + threadIdx.x;
  if (idx < (2 * OCCB / 4)) occ32[idx] = 0u;         // 14624 words = 2 planes
  if (idx < 256) {
    unsigned v = (idx < NBLK) ? 0u : 0x7FFFFFFFu;    // pad blocks: epoch = +inf
    flags[idx * FS] = v;
    flags[FP + idx * FS] = v;
  }
}

// ---------------------------------------------------------------------------
// Flag-based grid barrier, RMW-free, with dead-count payload (verified r3/r4).
// Arrival: one agent store of (epoch<<9)|count to the block's own 256B line.
// Poll: wave 0 loads all 256 flag entries (4/lane), shfl-min over epochs.
// Parity planes alternate per step -> at break every payload is this step's.
// ---------------------------------------------------------------------------
__device__ __forceinline__ int barrier_ps(unsigned int* flagbase, int epoch,
                                          int myblk, int* psB, const int* wcnt)
{
  __syncthreads();
  if (threadIdx.x == 0) {
    int c = wcnt[0] + wcnt[1] + wcnt[2] + wcnt[3];
    astore(&flagbase[myblk * FS], ((unsigned)epoch << 9) | (unsigned)c);
  }
  if (threadIdx.x < 64) {
    const int lane = threadIdx.x;
    unsigned v0, v1, v2, v3;
    for (;;) {
      v0 = aload(&flagbase[(lane      ) * FS]);
      v1 = aload(&flagbase[(lane +  64) * FS]);
      v2 = aload(&flagbase[(lane + 128) * FS]);
      v3 = aload(&flagbase[(lane + 192) * FS]);
      unsigned m0 = v0 >> 9, m1 = v1 >> 9, m2 = v2 >> 9, m3 = v3 >> 9;
      unsigned mn = m0 < m1 ? m0 : m1;
      unsigned mn2 = m2 < m3 ? m2 : m3;
      mn = mn < mn2 ? mn : mn2;
      for (int o = 32; o > 0; o >>= 1) {
        unsigned t = (unsigned)__shfl_xor((int)mn, o, 64);
        mn = mn < t ? mn : t;
      }
      if ((int)mn >= epoch) break;
      __builtin_amdgcn_s_sleep(1);
    }
    int acc = 0;
    if (lane       < myblk) acc += (int)(v0 & 511u);
    if (lane +  64 < myblk) acc += (int)(v1 & 511u);
    if (lane + 128 < myblk) acc += (int)(v2 & 511u);
    if (lane + 192 < myblk) acc += (int)(v3 & 511u);
    for (int o = 32; o > 0; o >>= 1) acc += __shfl_xor(acc, o, 64);
    if (lane == 0) *psB = acc;
  }
  __syncthreads();
  return *psB;
}

// ---------------------------------------------------------------------------
// Bilinear footprint at (xs,ys). Identical float ops to the verified kernels.
// ---------------------------------------------------------------------------
struct Bil {
  int x0i, x1i, y0i, y1i;
  int i00, i01, i10, i11;
  float w00, w01, w10, w11;
};

__device__ __forceinline__ Bil mkbil(float xs, float ys) {
#pragma clang fp contract(off)
  float x0 = floorf(xs), y0 = floorf(ys);
  float wx1 = xs - x0, wx0 = 1.0f - wx1;
  float wy1 = ys - y0, wy0 = 1.0f - wy1;
  Bil b;
  b.x0i = clampi((int)x0, 0, WW - 1);
  b.x1i = b.x0i + 1 > WW - 1 ? WW - 1 : b.x0i + 1;
  b.y0i = clampi((int)y0, 0, HH - 1);
  b.y1i = b.y0i + 1 > HH - 1 ? HH - 1 : b.y0i + 1;
  b.i00 = b.y0i * WW + b.x0i; b.i01 = b.y0i * WW + b.x1i;
  b.i10 = b.y1i * WW + b.x0i; b.i11 = b.y1i * WW + b.x1i;
  b.w00 = wy0 * wx0; b.w01 = wy0 * wx1;
  b.w10 = wy1 * wx0; b.w11 = wy1 * wx1;
  return b;
}

// Fwd-bwd consistency bit from pre-gathered backward-flow corner values.
__device__ __forceinline__ float prune_val(float fx, float fy,
    float c00a, float c01a, float c10a, float c11a,
    float c00b, float c01b, float c10b, float c11b, const Bil& t)
{
#pragma clang fp contract(off)
  float bw0 = ((c00a * t.w00 + c01a * t.w01) + c10a * t.w10) + c11a * t.w11;
  float bw1 = ((c00b * t.w00 + c01b * t.w01) + c10b * t.w10) + c11b * t.w11;
  float t0 = fx + bw0, t1 = fy + bw1;
  float diff = sqrtf(t0 * t0 + t1 * t1);
  float magf = sqrtf(fx * fx + fy * fy);
  float magb = sqrtf(bw0 * bw0 + bw1 * bw1);
  float mag = 0.5f * (magf + magb);
  return (diff <= 0.01f * mag + 0.1f) ? 1.0f : 0.0f;
}

// Integer-cell first-transition outcome {xt,yt,choose} packed as u64
// (choose encoded as yt<0). Bit-identical to the verified mode-2 path:
// at integer coords the bilinear weights degenerate exactly (w00=1, rest 0).
__device__ __forceinline__ unsigned long long make_intadv(
    int pix, int piy, float fx, float fy, const float* __restrict__ bks)
{
#pragma clang fp contract(off)
  float xt = (float)pix + fx, yt = (float)piy + fy;
  Bil Bt = mkbil(xt, yt);
  const float* b0p = bks;
  const float* b1p = bks + HW;
  float o = prune_val(fx, fy,
                      b0p[Bt.i00], b0p[Bt.i01], b0p[Bt.i10], b0p[Bt.i11],
                      b1p[Bt.i00], b1p[Bt.i01], b1p[Bt.i10], b1p[Bt.i11], Bt);
  bool marg = (xt > (float)MARGIN) && (yt > (float)MARGIN) &&
              (xt < (float)(WW - MARGIN)) && (yt < (float)(HH - MARGIN));
  bool ch = marg && (o > 0.5f);
  unsigned lo = __float_as_uint(ch ? xt : 0.0f);
  unsigned hi = __float_as_uint(ch ? yt : -1.0f);
  return ((unsigned long long)hi << 32) | (unsigned long long)lo;
}

// ---------------------------------------------------------------------------
// K1: persistent scan, ONE grid barrier per step, with an in-loop PRODUCER
// pipeline precomputing all integer-cell first transitions (intadv[k][g]):
//   intadv[k] is data-independent of the scan (fixed pixel, ff[k]/fbk[k]) ->
//   producer thread t (= cell t) computes it at CD(k-3) from loads issued
//   1-2 steps earlier; every load latency crosses a grid barrier. Born lanes
//   consume ONE pre-issued 8B agent load instead of the 2-round dependent
//   gather chain that round 4 exposed at Phase A (~1.5 us/step at 1 wave/SIMD).
// Occupancy tag planes are PARITY DOUBLE-BUFFERED: marks for step s+1 (tag
// s+1) go to plane (s+1)&1; compression at CD(s) reads that plane while
// next-step marks (tag s+2) go to the other plane — closes rounds 3/4's
// timing-margin race between a fast block's A(s+1) marks and a slow block's
// CD(s) compression reads.
// Stable order = word asc, bit asc = index asc (matches reference argsort).
// ---------------------------------------------------------------------------
__global__ __launch_bounds__(256, 1) void k_steps(
    const float* __restrict__ ff, const float* __restrict__ fbk,
    float* __restrict__ X, float* __restrict__ Y, float* __restrict__ Start,
    unsigned char* __restrict__ occ, unsigned int* __restrict__ flags,
    unsigned long long* __restrict__ intadv)
{
#pragma clang fp contract(off)
  const int tid = blockIdx.x * 256 + threadIdx.x;   // slot id
  const int lane = tid & 63;
  const int wv = threadIdx.x >> 6;                   // wave-in-block 0..3
  const unsigned long long ltmask = (1ull << lane) - 1ull;

  __shared__ unsigned long long wds[CWP];   // free-candidate bitmap (4 KB)
  __shared__ unsigned int pref[CWP];        // inclusive popcount prefix (2 KB)
  __shared__ int wsum[4];                   // scan partials
  __shared__ int wcnt[4];                   // per-wave dead counts
  __shared__ int psB;                       // lower-block dead total

  // Consumer slot state. mode: 0 dead, 1 pipelined, 2 integer-pos (pa64 valid).
  float x = 0.f, y = 0.f, st = -1.f;
  int mode = 0;
  float pf0 = 0.f, pf1 = 0.f, pf2 = 0.f, pf3 = 0.f;   // f0 at taps 00,01,10,11
  float pf4 = 0.f, pf5 = 0.f, pf6 = 0.f, pf7 = 0.f;   // f1 at taps 00,01,10,11
  float pb[32];                                        // b corner values, 8/tap
  float pxt = 0.f, pyt = 0.f;                          // advected candidate
  bool  pmarg = false;
  unsigned long long pa64 = (unsigned long long)0xBF800000u << 32;  // yt=-1

  // Producer state (thread t owns integer cell t, t < GG).
  const bool prod = (tid < GG);
  int pix = 0, piy = 0, pp = 0;
  float fNx = 0.f, fNy = 0.f;      // f(s+4) pair (issued last CD, arrives via barrier)
  float fCx = 0.f, fCy = 0.f;      // f(s+3) pair (arrived)
  float bC0 = 0.f, bC1 = 0.f, bC2 = 0.f, bC3 = 0.f;   // b(s+3) corners (in flight)
  float bC4 = 0.f, bC5 = 0.f, bC6 = 0.f, bC7 = 0.f;

  if (prod) {
    int ii = tid / GXC, jj = tid - ii * GXC;
    pix = MARGIN + STEP * jj; piy = MARGIN + STEP * ii;
    pp = piy * WW + pix;
    x = (float)pix; y = (float)piy;   // initial slot == producer cell
    st = 0.f; mode = 2;
  }
  X[tid] = x; Y[tid] = y;   // row 0

  // ---- Producer prologue: bootstrap intadv[0..2] + b(3)/f(4) in flight ----
  if (prod) {
    float f1x = ff[(size_t)1 * 2 * HW + pp], f1y = ff[(size_t)1 * 2 * HW + HW + pp];
    float f2x = ff[(size_t)2 * 2 * HW + pp], f2y = ff[(size_t)2 * 2 * HW + HW + pp];
    float f3x = ff[(size_t)3 * 2 * HW + pp], f3y = ff[(size_t)3 * 2 * HW + HW + pp];
    fNx = ff[(size_t)4 * 2 * HW + pp];       fNy = ff[(size_t)4 * 2 * HW + HW + pp];
    float f0x = ff[pp],                      f0y = ff[HW + pp];
    pa64 = make_intadv(pix, piy, f0x, f0y, fbk);               // own A(0) input
    astore64(&intadv[(size_t)1 * GG + tid],
             make_intadv(pix, piy, f1x, f1y, fbk + (size_t)1 * 2 * HW));
    astore64(&intadv[(size_t)2 * GG + tid],
             make_intadv(pix, piy, f2x, f2y, fbk + (size_t)2 * 2 * HW));
    {  // issue b(3) corners; consumed at CD(0)
      float xt = (float)pix + f3x, yt = (float)piy + f3y;
      Bil Bt = mkbil(xt, yt);
      const float* bb0 = fbk + (size_t)3 * 2 * HW;
      const float* bb1 = bb0 + HW;
      bC0 = bb0[Bt.i00]; bC1 = bb0[Bt.i01]; bC2 = bb0[Bt.i10]; bC3 = bb0[Bt.i11];
      bC4 = bb1[Bt.i00]; bC5 = bb1[Bt.i01]; bC6 = bb1[Bt.i10]; bC7 = bb1[Bt.i11];
      fCx = f3x; fCy = f3y;
    }
  }

// Issue the 32 b-corner loads for tap tt (consumed next iteration's A).
#define ISSUE_TAP(tt, TXI, TYI, FX, FY) do { \
    Bil Bt = mkbil((float)P.TXI + (FX), (float)P.TYI + (FY)); \
    pb[(tt)*8+0] = b0n[Bt.i00]; pb[(tt)*8+1] = b0n[Bt.i01]; \
    pb[(tt)*8+2] = b0n[Bt.i10]; pb[(tt)*8+3] = b0n[Bt.i11]; \
    pb[(tt)*8+4] = b1n[Bt.i00]; pb[(tt)*8+5] = b1n[Bt.i01]; \
    pb[(tt)*8+6] = b1n[Bt.i10]; pb[(tt)*8+7] = b1n[Bt.i11]; \
  } while (0)

// Recompute the identical footprint and fold pre-loaded values into the bit.
#define PRUNE_TAP(tt, TXI, TYI, FX, FY, OUT) do { \
    Bil Bt = mkbil((float)P.TXI + (FX), (float)P.TYI + (FY)); \
    OUT = prune_val((FX), (FY), \
                    pb[(tt)*8+0], pb[(tt)*8+1], pb[(tt)*8+2], pb[(tt)*8+3], \
                    pb[(tt)*8+4], pb[(tt)*8+5], pb[(tt)*8+6], pb[(tt)*8+7], Bt); \
  } while (0)

  for (int s = 0; s < SS - 1; ++s) {
    const float* f0n = ff + (size_t)(s + 1) * 2 * HW;  // NEXT step's fwd flow
    const float* f1n = f0n + HW;
    const unsigned char tag = (unsigned char)(s + 1);
    unsigned char* occw = occ + (((s + 1) & 1) ? OCCB : 0);   // this step's plane

    // ---- Phase A: prune decision (pure VALU) + occ tag marks --------------
    bool moved = false;
    if (mode == 1) {
      Bil P = mkbil(x, y);
      float o0, o1, o2, o3;
      PRUNE_TAP(0, x0i, y0i, pf0, pf4, o0);
      PRUNE_TAP(1, x1i, y0i, pf1, pf5, o1);
      PRUNE_TAP(2, x0i, y1i, pf2, pf6, o2);
      PRUNE_TAP(3, x1i, y1i, pf3, pf7, o3);
      float fbv = ((o0 * P.w00 + o1 * P.w01) + o2 * P.w10) + o3 * P.w11;
      if (pmarg && fbv > 0.5f) {
        x = pxt; y = pyt;
        Bil Pn = mkbil(x, y);                 // prefetch f for step s+1
        pf0 = f0n[Pn.i00]; pf1 = f0n[Pn.i01]; pf2 = f0n[Pn.i10]; pf3 = f0n[Pn.i11];
        pf4 = f1n[Pn.i00]; pf5 = f1n[Pn.i01]; pf6 = f1n[Pn.i10]; pf7 = f1n[Pn.i11];
        moved = true;
      } else { st = -1.f; x = 0.f; y = 0.f; mode = 0; }
    } else if (mode == 2) {
      // Integer position: precomputed outcome (pre-issued 8B load).
      float axt = __uint_as_float((unsigned)pa64);
      float ayt = __uint_as_float((unsigned)(pa64 >> 32));
      if (ayt >= 0.0f) {                      // choose (yt > MARGIN when set)
        x = axt; y = ayt; mode = 1;
        Bil Pn = mkbil(x, y);                 // prefetch f for step s+1
        pf0 = f0n[Pn.i00]; pf1 = f0n[Pn.i01]; pf2 = f0n[Pn.i10]; pf3 = f0n[Pn.i11];
        pf4 = f1n[Pn.i00]; pf5 = f1n[Pn.i01]; pf6 = f1n[Pn.i10]; pf7 = f1n[Pn.i11];
        moved = true;
      } else { st = -1.f; x = 0.f; y = 0.f; mode = 0; }
    }
    if (moved) {
      int oy = (int)y, ox = (int)x;   // trunc == floor (positive)
      int i0 = ((oy - (MARGIN + 2) + 4099) >> 2) - 1024;  // ceil((oy-12)/4)
      int i1 = ((oy - (MARGIN - 2) + 4096) >> 2) - 1024;  // floor((oy-8)/4)
      int j0 = ((ox - (MARGIN + 2) + 4099) >> 2) - 1024;
      int j1 = ((ox - (MARGIN - 2) + 4096) >> 2) - 1024;
      if (i0 < 0) i0 = 0; if (i1 > GYC - 1) i1 = GYC - 1;
      if (j0 < 0) j0 = 0; if (j1 > GXC - 1) j1 = GXC - 1;
      for (int i = i0; i <= i1; ++i)
        for (int j = j0; j <= j1; ++j)
          astore8(&occw[i * GXC + j], tag);   // same-value stores: benign race
    }
    unsigned long long smask = __ballot(st < 0.0f);
    if (lane == 0) wcnt[wv] = (int)__popcll(smask);

    int ps = barrier_ps(flags + (s & 1) * FP, s + 1, blockIdx.x, &psB, wcnt);

    // ---- Phase CD --------------------------------------------------------
    // Compression pass: 15 independent coalesced u64 agent loads (issue all
    // first -> one latency exposure), SWAR byte-compare vs tag below.
    unsigned long long cv[16];
    {
      const unsigned long long* occ64 =
          (const unsigned long long*)(occ + (((s + 1) & 1) ? OCCB : 0));
      int t = threadIdx.x;
#pragma unroll
      for (int r = 0; r < 16; ++r) {
        int j = t + 256 * r;
        cv[r] = (j < GG / 8) ? aload64(&occ64[j]) : 0ull;   // GG/8 = 3654
      }
    }
    // Pipelined consumer: advect + issue 32 b(s+1) loads (soak under CD).
    if (mode == 1 && s < SS - 2) {
      Bil P = mkbil(x, y);
      float u_ = ((pf0 * P.w00 + pf1 * P.w01) + pf2 * P.w10) + pf3 * P.w11;
      float v_ = ((pf4 * P.w00 + pf5 * P.w01) + pf6 * P.w10) + pf7 * P.w11;
      pxt = x + u_; pyt = y + v_;
      pmarg = (pxt > (float)MARGIN) && (pyt > (float)MARGIN) &&
              (pxt < (float)(WW - MARGIN)) && (pyt < (float)(HH - MARGIN));
      const float* b0n = fbk + (size_t)(s + 1) * 2 * HW;
      const float* b1n = b0n + HW;
      ISSUE_TAP(0, x0i, y0i, pf0, pf4);
      ISSUE_TAP(1, x1i, y0i, pf1, pf5);
      ISSUE_TAP(2, x0i, y1i, pf2, pf6);
      ISSUE_TAP(3, x1i, y1i, pf3, pf7);
    }
    // Producer: compute+publish intadv[s+3]; issue b(s+4); issue f(s+5).
    if (prod) {
      if (s <= SS - 5) {                       // k = s+3 <= 30
        float xt = (float)pix + fCx, yt = (float)piy + fCy;
        Bil Bt = mkbil(xt, yt);
        float o = prune_val(fCx, fCy, bC0, bC1, bC2, bC3, bC4, bC5, bC6, bC7, Bt);
        bool marg = (xt > (float)MARGIN) && (yt > (float)MARGIN) &&
                    (xt < (float)(WW - MARGIN)) && (yt < (float)(HH - MARGIN));
        bool ch = marg && (o > 0.5f);
        unsigned lo = __float_as_uint(ch ? xt : 0.0f);
        unsigned hi = __float_as_uint(ch ? yt : -1.0f);
        astore64(&intadv[(size_t)(s + 3) * GG + tid],
                 ((unsigned long long)hi << 32) | (unsigned long long)lo);
      }
      if (s <= SS - 6) {                       // issue b(s+4), f(s+4) arrived
        float xt = (float)pix + fNx, yt = (float)piy + fNy;
        Bil Bt = mkbil(xt, yt);
        const float* bb0 = fbk + (size_t)(s + 4) * 2 * HW;
        const float* bb1 = bb0 + HW;
        bC0 = bb0[Bt.i00]; bC1 = bb0[Bt.i01]; bC2 = bb0[Bt.i10]; bC3 = bb0[Bt.i11];
        bC4 = bb1[Bt.i00]; bC5 = bb1[Bt.i01]; bC6 = bb1[Bt.i10]; bC7 = bb1[Bt.i11];
        fCx = fNx; fCy = fNy;
      }
      if (s <= SS - 7) {                       // issue static f(s+5)
        const float* fp_ = ff + (size_t)(s + 5) * 2 * HW;
        fNx = fp_[pp]; fNy = fp_[HW + pp];
      }
    }
    // SWAR: byte c of cv[r] is cell 8j+c; free = byte != tag -> bit c.
    {
      unsigned char* nb = (unsigned char*)wds;
      const unsigned long long tr = 0x0101010101010101ull * (unsigned long long)tag;
      int t = threadIdx.x;
#pragma unroll
      for (int r = 0; r < 16; ++r) {
        int j = t + 256 * r;
        unsigned long long xx = cv[r] ^ tr;
        unsigned long long t1 = (xx & 0x7F7F7F7F7F7F7F7Full) + 0x7F7F7F7F7F7F7F7Full;
        unsigned long long nz = ((t1 | xx) >> 7) & 0x0101010101010101ull;
        unsigned char byte = (unsigned char)((nz * 0x0102040810204080ull) >> 56);
        nb[j] = (j < GG / 8) ? byte : (unsigned char)0;   // pads (incl. word 456 tail) zero
      }
    }
    __syncthreads();
    // Popcount prefix over the bitmap (shuffle scan, as verified).
    {
      int t = threadIdx.x;
      int e0 = 2 * t, e1 = 2 * t + 1;
      unsigned long long m0 = wds[e0];
      unsigned long long m1 = wds[e1];
      int p0 = __popcll(m0), p1 = __popcll(m1);
      int v = p0 + p1;
      for (int o = 1; o < 64; o <<= 1) {
        int uu = __shfl_up(v, o, 64);
        if (lane >= o) v += uu;
      }
      if (lane == 63) wsum[wv] = v;
      __syncthreads();
      int base = 0;
      for (int j2 = 0; j2 < wv; ++j2) base += wsum[j2];
      pref[e0] = (unsigned int)(base + v - p1);
      pref[e1] = (unsigned int)(base + v);
      __syncthreads();
    }
    int tc = (int)pref[CWP - 1];              // total free candidates

    // dead-slot rank: lower blocks (flag payloads) + lower waves + lower lanes
    int lower = 0;
    for (int j2 = 0; j2 < wv; ++j2) lower += wcnt[j2];

    if (st < 0.0f) {
      int r = ps + lower + (int)__popcll(smask & ltmask);
      if (r < tc) {                  // r < min(num_cand, num_free) <=> r < num_cand
        // word k containing rank r: largest k with pref[k-1] <= r
        int k = 0;
        for (int b = 256; b >= 1; b >>= 1) {
          int nk = k + b;
          if (nk <= CWP - 1 && (int)pref[nk - 1] <= r) k = nk;
        }
        int j = r - (k ? (int)pref[k - 1] : 0);
        unsigned long long m = wds[k];
        int lo = 0;                  // position of the (j+1)-th set bit
        for (int b = 32; b >= 1; b >>= 1) {
          int nb = lo + b;
          unsigned long long mask = (nb >= 64) ? ~0ull : ((1ull << nb) - 1ull);
          if (__popcll(m & mask) <= j) lo = nb;
        }
        int g = k * 64 + lo;
        int ii = g / GXC, jj = g - ii * GXC;
        x = (float)(MARGIN + STEP * jj);
        y = (float)(MARGIN + STEP * ii);
        st = (float)(s + 1);
        mode = 2;
        if (s < SS - 2)              // at s=30 there is no A(31): skip the load
          pa64 = aload64(&intadv[(size_t)(s + 1) * GG + g]);   // in flight to A(s+1)
      }
    }
    X[(size_t)(s + 1) * NSLOT + tid] = x;
    Y[(size_t)(s + 1) * NSLOT + tid] = y;
    __syncthreads();   // protect wcnt (read above) from next A's writes
  }

#undef ISSUE_TAP
#undef PRUNE_TAP

  Start[tid] = st;
}

// ---------------------------------------------------------------------------
extern "C" void kernel_launch(void* const* d_in, const int* in_sizes, int n_in,
                              void* d_out, int out_size, void* d_ws, size_t ws_size,
                              hipStream_t stream) {
  const float* ff  = (const float*)d_in[0];   // (1,S,2,H,W)
  const float* fbk = (const float*)d_in[1];

  float* X     = (float*)d_out;                       // (S, N)
  float* Y     = X + (size_t)SS * NSLOT;              // (S, N)
  float* Start = Y + (size_t)SS * NSLOT;              // (N,)

  unsigned int*       flags  = (unsigned int*)d_ws;                  // 128 KB
  unsigned char*      occ    = (unsigned char*)(flags + 2 * FP);     // 2 planes
  unsigned long long* intadv = (unsigned long long*)(occ + 2 * OCCB); // 31*GG u64

  k_init<<<58, 256, 0, stream>>>(flags, (unsigned int*)occ);

  k_steps<<<NBLK, 256, 0, stream>>>(ff, fbk, X, Y, Start, occ, flags, intadv);
}

// Round 6
// 428.612 us; speedup vs baseline: 3.2087x; 1.0069x over previous
//
#include <hip/hip_runtime.h>
#include <cstdint>

// Problem constants (fixed by setup_inputs: H=480, W=1024, S=32, margin=10, step=4)
#define HH 480
#define WW 1024
#define SS 32
#define HW (HH*WW)              // 491520
#define MARGIN 10
#define STEP 4
#define GYC 116                 // len(arange(10, 471, 4))
#define GXC 252                 // len(arange(10, 1015, 4))
#define GG (GYC*GXC)            // 29232 grid candidates (= 456*64 + 48)
#define NSLOT (2*HH*WW/(STEP*STEP))  // 61440 trajectory slots
#define NBLK (NSLOT/256)        // 240 blocks -> co-resident on 256 CUs
#define NWAVE (NSLOT/64)        // 960 waves
#define CW ((GG+63)/64)         // 457 candidate bitmap words
#define CWP 512                 // padded word count (per-block scan width)
#define OCCB (CW*64)            // 29248 bytes per occupancy plane
#define FS8 32                  // u64 stride between flag entries (256 B line)
#define FP8 (256*FS8)           // u64 offset between the two parity planes
#define CPB 122                 // producer cells per block (240*122 >= GG)

// Agent-scope (device-coherent) accessors.
__device__ __forceinline__ unsigned int aload(const unsigned int* p) {
  return __hip_atomic_load(p, __ATOMIC_RELAXED, __HIP_MEMORY_SCOPE_AGENT);
}
__device__ __forceinline__ void astore(unsigned int* p, unsigned int v) {
  __hip_atomic_store(p, v, __ATOMIC_RELAXED, __HIP_MEMORY_SCOPE_AGENT);
}
__device__ __forceinline__ unsigned long long aload64(const unsigned long long* p) {
  return __hip_atomic_load(p, __ATOMIC_RELAXED, __HIP_MEMORY_SCOPE_AGENT);
}
__device__ __forceinline__ void astore64(unsigned long long* p, unsigned long long v) {
  __hip_atomic_store(p, v, __ATOMIC_RELAXED, __HIP_MEMORY_SCOPE_AGENT);
}
__device__ __forceinline__ void astore8(unsigned char* p, unsigned char v) {
  __hip_atomic_store(p, v, __ATOMIC_RELAXED, __HIP_MEMORY_SCOPE_AGENT);
}

__device__ __forceinline__ int clampi(int v, int lo, int hi) {
  return v < lo ? lo : (v > hi ? hi : v);
}

// ---------------------------------------------------------------------------
// K0: zero BOTH occupancy tag planes + init both parity flag planes.
// ---------------------------------------------------------------------------
__global__ __launch_bounds__(256) void k_init(unsigned long long* __restrict__ flags,
                                              unsigned int* __restrict__ occ32)
{
  int idx = blockIdx.x * 256 + threadIdx.x;
  if (idx < (2 * OCCB / 4)) occ32[idx] = 0u;         // 14624 words = 2 planes
  if (idx < 256) {
    unsigned long long v = (idx < NBLK) ? 0ull : (0x7FFFFFFFull << 32); // pads: +inf
    flags[idx * FS8] = v;
    flags[FP8 + idx * FS8] = v;
  }
}

// ---------------------------------------------------------------------------
// Flag-based grid barrier, RMW-free, u64 payload = epoch<<32 | 4x8-bit
// per-WAVE dead counts (slots are wave-permuted: slot-wave sw = wv*240 + b).
// Arrival: one agent u64 store to the block's own 256B line. Poll: wave 0
// loads all 256 entries (4/lane), shfl-min over epochs. Parity planes
// alternate per step -> at break every payload is exactly this step's.
// Rank prefixes: unpack counts to 4x16-bit packed u64; two packed butterfly
// reduces give P_v (blocks < myblk, per wave-row v) and F_v (all blocks);
// ps(v) = sum_{v'<v} F_v' + P_v — exact slot-index-ordered dead ranks.
// Safe: 240 blocks co-resident; __syncthreads drains vmcnt before the flag
// store, so all marks/data stores precede arrival (same as prior rounds).
// ---------------------------------------------------------------------------
__device__ __forceinline__ void barrier_ps4(unsigned long long* flagbase, int epoch,
                                            int myblk, int* ps4, const int* wcnt)
{
  __syncthreads();
  if (threadIdx.x == 0) {
    unsigned cpack = (unsigned)wcnt[0] | ((unsigned)wcnt[1] << 8)
                   | ((unsigned)wcnt[2] << 16) | ((unsigned)wcnt[3] << 24);
    astore64(&flagbase[myblk * FS8],
             ((unsigned long long)(unsigned)epoch << 32) | (unsigned long long)cpack);
  }
  if (threadIdx.x < 64) {
    const int lane = threadIdx.x;
    unsigned long long v0, v1, v2, v3;
    for (;;) {
      v0 = aload64(&flagbase[(lane      ) * FS8]);
      v1 = aload64(&flagbase[(lane +  64) * FS8]);
      v2 = aload64(&flagbase[(lane + 128) * FS8]);
      v3 = aload64(&flagbase[(lane + 192) * FS8]);
      unsigned m0 = (unsigned)(v0 >> 32), m1 = (unsigned)(v1 >> 32);
      unsigned m2 = (unsigned)(v2 >> 32), m3 = (unsigned)(v3 >> 32);
      unsigned mn = m0 < m1 ? m0 : m1;
      unsigned mn2 = m2 < m3 ? m2 : m3;
      mn = mn < mn2 ? mn : mn2;
      for (int o = 32; o > 0; o >>= 1) {
        unsigned t = (unsigned)__shfl_xor((int)mn, o, 64);
        mn = mn < t ? mn : t;
      }
      if ((int)mn >= epoch) break;
      __builtin_amdgcn_s_sleep(1);
    }
    // unpack 4x8 -> 4x16 packed u64 (field sums <= 240*64 = 15360 < 65536)
    auto up = [](unsigned long long f) -> unsigned long long {
      unsigned c = (unsigned)f;
      return (unsigned long long)(c & 0xFFu)
           | ((unsigned long long)((c >>  8) & 0xFFu) << 16)
           | ((unsigned long long)((c >> 16) & 0xFFu) << 32)
           | ((unsigned long long)((c >> 24) & 0xFFu) << 48);
    };
    unsigned long long u0 = up(v0), u1 = up(v1), u2 = up(v2), u3 = up(v3);
    unsigned long long F = u0 + u1 + u2 + u3;
    unsigned long long P = (lane       < myblk ? u0 : 0ull)
                         + (lane +  64 < myblk ? u1 : 0ull)
                         + (lane + 128 < myblk ? u2 : 0ull)
                         + (lane + 192 < myblk ? u3 : 0ull);
    for (int o = 32; o > 0; o >>= 1) {
      unsigned flo = (unsigned)F, fhi = (unsigned)(F >> 32);
      unsigned plo = (unsigned)P, phi = (unsigned)(P >> 32);
      unsigned flo2 = (unsigned)__shfl_xor((int)flo, o, 64);
      unsigned fhi2 = (unsigned)__shfl_xor((int)fhi, o, 64);
      unsigned plo2 = (unsigned)__shfl_xor((int)plo, o, 64);
      unsigned phi2 = (unsigned)__shfl_xor((int)phi, o, 64);
      F += ((unsigned long long)fhi2 << 32) | flo2;
      P += ((unsigned long long)phi2 << 32) | plo2;
    }
    if (lane == 0) {
      int f0 = (int)(F & 0xFFFF), f1 = (int)((F >> 16) & 0xFFFF), f2 = (int)((F >> 32) & 0xFFFF);
      int p0 = (int)(P & 0xFFFF), p1 = (int)((P >> 16) & 0xFFFF);
      int p2 = (int)((P >> 32) & 0xFFFF), p3 = (int)((P >> 48) & 0xFFFF);
      ps4[0] = p0;
      ps4[1] = f0 + p1;
      ps4[2] = f0 + f1 + p2;
      ps4[3] = f0 + f1 + f2 + p3;
    }
  }
  __syncthreads();
}

// ---------------------------------------------------------------------------
// Bilinear footprint at (xs,ys). Identical float ops to the verified kernels.
// ---------------------------------------------------------------------------
struct Bil {
  int x0i, x1i, y0i, y1i;
  int i00, i01, i10, i11;
  float w00, w01, w10, w11;
};

__device__ __forceinline__ Bil mkbil(float xs, float ys) {
#pragma clang fp contract(off)
  float x0 = floorf(xs), y0 = floorf(ys);
  float wx1 = xs - x0, wx0 = 1.0f - wx1;
  float wy1 = ys - y0, wy0 = 1.0f - wy1;
  Bil b;
  b.x0i = clampi((int)x0, 0, WW - 1);
  b.x1i = b.x0i + 1 > WW - 1 ? WW - 1 : b.x0i + 1;
  b.y0i = clampi((int)y0, 0, HH - 1);
  b.y1i = b.y0i + 1 > HH - 1 ? HH - 1 : b.y0i + 1;
  b.i00 = b.y0i * WW + b.x0i; b.i01 = b.y0i * WW + b.x1i;
  b.i10 = b.y1i * WW + b.x0i; b.i11 = b.y1i * WW + b.x1i;
  b.w00 = wy0 * wx0; b.w01 = wy0 * wx1;
  b.w10 = wy1 * wx0; b.w11 = wy1 * wx1;
  return b;
}

// Fwd-bwd consistency bit from pre-gathered backward-flow corner values.
__device__ __forceinline__ float prune_val(float fx, float fy,
    float c00a, float c01a, float c10a, float c11a,
    float c00b, float c01b, float c10b, float c11b, const Bil& t)
{
#pragma clang fp contract(off)
  float bw0 = ((c00a * t.w00 + c01a * t.w01) + c10a * t.w10) + c11a * t.w11;
  float bw1 = ((c00b * t.w00 + c01b * t.w01) + c10b * t.w10) + c11b * t.w11;
  float t0 = fx + bw0, t1 = fy + bw1;
  float diff = sqrtf(t0 * t0 + t1 * t1);
  float magf = sqrtf(fx * fx + fy * fy);
  float magb = sqrtf(bw0 * bw0 + bw1 * bw1);
  float mag = 0.5f * (magf + magb);
  return (diff <= 0.01f * mag + 0.1f) ? 1.0f : 0.0f;
}

// Integer-cell first-transition outcome {xt,yt,choose} packed as u64
// (choose encoded as yt<0). Bit-identical to the verified mode-2 path.
__device__ __forceinline__ unsigned long long make_intadv(
    int pix, int piy, float fx, float fy, const float* __restrict__ bks)
{
#pragma clang fp contract(off)
  float xt = (float)pix + fx, yt = (float)piy + fy;
  Bil Bt = mkbil(xt, yt);
  const float* b0p = bks;
  const float* b1p = bks + HW;
  float o = prune_val(fx, fy,
                      b0p[Bt.i00], b0p[Bt.i01], b0p[Bt.i10], b0p[Bt.i11],
                      b1p[Bt.i00], b1p[Bt.i01], b1p[Bt.i10], b1p[Bt.i11], Bt);
  bool marg = (xt > (float)MARGIN) && (yt > (float)MARGIN) &&
              (xt < (float)(WW - MARGIN)) && (yt < (float)(HH - MARGIN));
  bool ch = marg && (o > 0.5f);
  unsigned lo = __float_as_uint(ch ? xt : 0.0f);
  unsigned hi = __float_as_uint(ch ? yt : -1.0f);
  return ((unsigned long long)hi << 32) | (unsigned long long)lo;
}

// ---------------------------------------------------------------------------
// K1: persistent scan, ONE grid barrier per step. Round-6 changes (work is
// byte-identical; only thread->work assignment moves):
//  * SLOT WAVE-PERMUTATION: thread (b,wv,lane) owns slot (wv*240+b)*64+lane.
//    Alive slots (first 457 slot-waves) spread ~2 waves/block across all 240
//    blocks instead of saturating blocks 0-114 — scattered-gather traffic
//    (f-prefetch, pb taps, marks) now uses all 256 CUs' L1/TA ports, and the
//    per-step barrier no longer waits on a half-idle machine.
//  * Dead-rank order (slot-index asc) preserved exactly via per-wave counts
//    in the u64 barrier payload + packed prefix reduce (see barrier_ps4).
//  * PRODUCERS DISTRIBUTED: cell b*122+(t>>1) on even threads, all blocks.
//  * wcnt parity-double-buffered -> trailing __syncthreads removed.
// ---------------------------------------------------------------------------
__global__ __launch_bounds__(256, 1) void k_steps(
    const float* __restrict__ ff, const float* __restrict__ fbk,
    float* __restrict__ X, float* __restrict__ Y, float* __restrict__ Start,
    unsigned char* __restrict__ occ, unsigned long long* __restrict__ flags,
    unsigned long long* __restrict__ intadv)
{
#pragma clang fp contract(off)
  const int b = blockIdx.x;
  const int lane = threadIdx.x & 63;
  const int wv = threadIdx.x >> 6;                   // wave-in-block 0..3
  const int slot = ((wv * NBLK + b) << 6) | lane;    // wave-permuted slot id
  const unsigned long long ltmask = (1ull << lane) - 1ull;

  __shared__ unsigned long long wds[CWP];   // free-candidate bitmap (4 KB)
  __shared__ unsigned int pref[CWP];        // inclusive popcount prefix (2 KB)
  __shared__ int wsum[4];                   // scan partials
  __shared__ int wcnt[2][4];                // per-wave dead counts (parity)
  __shared__ int ps4[4];                    // per-wave lower-rank totals

  // Consumer slot state. mode: 0 dead, 1 pipelined, 2 integer-pos (pa64 valid).
  float x = 0.f, y = 0.f, st = -1.f;
  int mode = 0;
  float pf0 = 0.f, pf1 = 0.f, pf2 = 0.f, pf3 = 0.f;   // f0 at taps 00,01,10,11
  float pf4 = 0.f, pf5 = 0.f, pf6 = 0.f, pf7 = 0.f;   // f1 at taps 00,01,10,11
  float pb[32];                                        // b corner values, 8/tap
  float pxt = 0.f, pyt = 0.f;                          // advected candidate
  bool  pmarg = false;
  unsigned long long pa64 = (unsigned long long)0xBF800000u << 32;  // yt=-1

  // Producer identity (decoupled from slot): even threads, ~30 cells/wave.
  const int pj = threadIdx.x >> 1;
  const int pcell = b * CPB + pj;
  const bool prod = ((threadIdx.x & 1) == 0) && (pj < CPB) && (pcell < GG);
  int pix = 0, piy = 0, pp = 0;
  float fNx = 0.f, fNy = 0.f;      // f(s+4) pair (issued last CD)
  float fCx = 0.f, fCy = 0.f;      // f(s+3) pair (arrived)
  float bC0 = 0.f, bC1 = 0.f, bC2 = 0.f, bC3 = 0.f;   // b(s+3) corners
  float bC4 = 0.f, bC5 = 0.f, bC6 = 0.f, bC7 = 0.f;

  // ---- Slot prologue: initial alive slots compute their own A(0) input ----
  if (slot < GG) {
    int ii = slot / GXC, jj = slot - ii * GXC;
    int ix = MARGIN + STEP * jj, iy = MARGIN + STEP * ii;
    x = (float)ix; y = (float)iy;
    st = 0.f; mode = 2;
    int p0_ = iy * WW + ix;
    float f0x = ff[p0_], f0y = ff[HW + p0_];
    pa64 = make_intadv(ix, iy, f0x, f0y, fbk);
  }
  X[slot] = x; Y[slot] = y;   // row 0

  // ---- Producer prologue: bootstrap intadv[1..2] + b(3)/f(4) in flight ----
  if (prod) {
    int ii = pcell / GXC, jj = pcell - ii * GXC;
    pix = MARGIN + STEP * jj; piy = MARGIN + STEP * ii;
    pp = piy * WW + pix;
    float f1x = ff[(size_t)1 * 2 * HW + pp], f1y = ff[(size_t)1 * 2 * HW + HW + pp];
    float f2x = ff[(size_t)2 * 2 * HW + pp], f2y = ff[(size_t)2 * 2 * HW + HW + pp];
    float f3x = ff[(size_t)3 * 2 * HW + pp], f3y = ff[(size_t)3 * 2 * HW + HW + pp];
    fNx = ff[(size_t)4 * 2 * HW + pp];       fNy = ff[(size_t)4 * 2 * HW + HW + pp];
    astore64(&intadv[(size_t)1 * GG + pcell],
             make_intadv(pix, piy, f1x, f1y, fbk + (size_t)1 * 2 * HW));
    astore64(&intadv[(size_t)2 * GG + pcell],
             make_intadv(pix, piy, f2x, f2y, fbk + (size_t)2 * 2 * HW));
    {  // issue b(3) corners; consumed at CD(0)
      float xt = (float)pix + f3x, yt = (float)piy + f3y;
      Bil Bt = mkbil(xt, yt);
      const float* bb0 = fbk + (size_t)3 * 2 * HW;
      const float* bb1 = bb0 + HW;
      bC0 = bb0[Bt.i00]; bC1 = bb0[Bt.i01]; bC2 = bb0[Bt.i10]; bC3 = bb0[Bt.i11];
      bC4 = bb1[Bt.i00]; bC5 = bb1[Bt.i01]; bC6 = bb1[Bt.i10]; bC7 = bb1[Bt.i11];
      fCx = f3x; fCy = f3y;
    }
  }

// Issue the 32 b-corner loads for tap tt (consumed next iteration's A).
#define ISSUE_TAP(tt, TXI, TYI, FX, FY) do { \
    Bil Bt = mkbil((float)P.TXI + (FX), (float)P.TYI + (FY)); \
    pb[(tt)*8+0] = b0n[Bt.i00]; pb[(tt)*8+1] = b0n[Bt.i01]; \
    pb[(tt)*8+2] = b0n[Bt.i10]; pb[(tt)*8+3] = b0n[Bt.i11]; \
    pb[(tt)*8+4] = b1n[Bt.i00]; pb[(tt)*8+5] = b1n[Bt.i01]; \
    pb[(tt)*8+6] = b1n[Bt.i10]; pb[(tt)*8+7] = b1n[Bt.i11]; \
  } while (0)

// Recompute the identical footprint and fold pre-loaded values into the bit.
#define PRUNE_TAP(tt, TXI, TYI, FX, FY, OUT) do { \
    Bil Bt = mkbil((float)P.TXI + (FX), (float)P.TYI + (FY)); \
    OUT = prune_val((FX), (FY), \
                    pb[(tt)*8+0], pb[(tt)*8+1], pb[(tt)*8+2], pb[(tt)*8+3], \
                    pb[(tt)*8+4], pb[(tt)*8+5], pb[(tt)*8+6], pb[(tt)*8+7], Bt); \
  } while (0)

  for (int s = 0; s < SS - 1; ++s) {
    const float* f0n = ff + (size_t)(s + 1) * 2 * HW;  // NEXT step's fwd flow
    const float* f1n = f0n + HW;
    const unsigned char tag = (unsigned char)(s + 1);
    unsigned char* occw = occ + (((s + 1) & 1) ? OCCB : 0);   // this step's plane

    // ---- Phase A: prune decision (pure VALU) + occ tag marks --------------
    bool moved = false;
    if (mode == 1) {
      Bil P = mkbil(x, y);
      float o0, o1, o2, o3;
      PRUNE_TAP(0, x0i, y0i, pf0, pf4, o0);
      PRUNE_TAP(1, x1i, y0i, pf1, pf5, o1);
      PRUNE_TAP(2, x0i, y1i, pf2, pf6, o2);
      PRUNE_TAP(3, x1i, y1i, pf3, pf7, o3);
      float fbv = ((o0 * P.w00 + o1 * P.w01) + o2 * P.w10) + o3 * P.w11;
      if (pmarg && fbv > 0.5f) {
        x = pxt; y = pyt;
        Bil Pn = mkbil(x, y);                 // prefetch f for step s+1
        pf0 = f0n[Pn.i00]; pf1 = f0n[Pn.i01]; pf2 = f0n[Pn.i10]; pf3 = f0n[Pn.i11];
        pf4 = f1n[Pn.i00]; pf5 = f1n[Pn.i01]; pf6 = f1n[Pn.i10]; pf7 = f1n[Pn.i11];
        moved = true;
      } else { st = -1.f; x = 0.f; y = 0.f; mode = 0; }
    } else if (mode == 2) {
      // Integer position: precomputed outcome (pre-issued 8B load).
      float axt = __uint_as_float((unsigned)pa64);
      float ayt = __uint_as_float((unsigned)(pa64 >> 32));
      if (ayt >= 0.0f) {                      // choose
        x = axt; y = ayt; mode = 1;
        Bil Pn = mkbil(x, y);                 // prefetch f for step s+1
        pf0 = f0n[Pn.i00]; pf1 = f0n[Pn.i01]; pf2 = f0n[Pn.i10]; pf3 = f0n[Pn.i11];
        pf4 = f1n[Pn.i00]; pf5 = f1n[Pn.i01]; pf6 = f1n[Pn.i10]; pf7 = f1n[Pn.i11];
        moved = true;
      } else { st = -1.f; x = 0.f; y = 0.f; mode = 0; }
    }
    if (moved) {
      int oy = (int)y, ox = (int)x;   // trunc == floor (positive)
      int i0 = ((oy - (MARGIN + 2) + 4099) >> 2) - 1024;  // ceil((oy-12)/4)
      int i1 = ((oy - (MARGIN - 2) + 4096) >> 2) - 1024;  // floor((oy-8)/4)
      int j0 = ((ox - (MARGIN + 2) + 4099) >> 2) - 1024;
      int j1 = ((ox - (MARGIN - 2) + 4096) >> 2) - 1024;
      if (i0 < 0) i0 = 0; if (i1 > GYC - 1) i1 = GYC - 1;
      if (j0 < 0) j0 = 0; if (j1 > GXC - 1) j1 = GXC - 1;
      for (int i = i0; i <= i1; ++i)
        for (int j = j0; j <= j1; ++j)
          astore8(&occw[i * GXC + j], tag);   // same-value stores: benign race
    }
    unsigned long long smask = __ballot(st < 0.0f);
    if (lane == 0) wcnt[s & 1][wv] = (int)__popcll(smask);

    barrier_ps4(flags + (s & 1) * FP8, s + 1, b, ps4, wcnt[s & 1]);
    int ps = ps4[wv];

    // ---- Phase CD --------------------------------------------------------
    // Compression: 15 independent coalesced u64 agent loads (one exposure).
    unsigned long long cv[16];
    {
      const unsigned long long* occ64 =
          (const unsigned long long*)(occ + (((s + 1) & 1) ? OCCB : 0));
      int t = threadIdx.x;
#pragma unroll
      for (int r = 0; r < 16; ++r) {
        int j = t + 256 * r;
        cv[r] = (j < GG / 8) ? aload64(&occ64[j]) : 0ull;   // GG/8 = 3654
      }
    }
    // Pipelined consumer: advect + issue 32 b(s+1) loads (soak under CD).
    if (mode == 1 && s < SS - 2) {
      Bil P = mkbil(x, y);
      float u_ = ((pf0 * P.w00 + pf1 * P.w01) + pf2 * P.w10) + pf3 * P.w11;
      float v_ = ((pf4 * P.w00 + pf5 * P.w01) + pf6 * P.w10) + pf7 * P.w11;
      pxt = x + u_; pyt = y + v_;
      pmarg = (pxt > (float)MARGIN) && (pyt > (float)MARGIN) &&
              (pxt < (float)(WW - MARGIN)) && (pyt < (float)(HH - MARGIN));
      const float* b0n = fbk + (size_t)(s + 1) * 2 * HW;
      const float* b1n = b0n + HW;
      ISSUE_TAP(0, x0i, y0i, pf0, pf4);
      ISSUE_TAP(1, x1i, y0i, pf1, pf5);
      ISSUE_TAP(2, x0i, y1i, pf2, pf6);
      ISSUE_TAP(3, x1i, y1i, pf3, pf7);
    }
    // Producer: compute+publish intadv[s+3]; issue b(s+4); issue f(s+5).
    if (prod) {
      if (s <= SS - 5) {                       // k = s+3 <= 30
        float xt = (float)pix + fCx, yt = (float)piy + fCy;
        Bil Bt = mkbil(xt, yt);
        float o = prune_val(fCx, fCy, bC0, bC1, bC2, bC3, bC4, bC5, bC6, bC7, Bt);
        bool marg = (xt > (float)MARGIN) && (yt > (float)MARGIN) &&
                    (xt < (float)(WW - MARGIN)) && (yt < (float)(HH - MARGIN));
        bool ch = marg && (o > 0.5f);
        unsigned lo = __float_as_uint(ch ? xt : 0.0f);
        unsigned hi = __float_as_uint(ch ? yt : -1.0f);
        astore64(&intadv[(size_t)(s + 3) * GG + pcell],
                 ((unsigned long long)hi << 32) | (unsigned long long)lo);
      }
      if (s <= SS - 6) {                       // issue b(s+4), f(s+4) arrived
        float xt = (float)pix + fNx, yt = (float)piy + fNy;
        Bil Bt = mkbil(xt, yt);
        const float* bb0 = fbk + (size_t)(s + 4) * 2 * HW;
        const float* bb1 = bb0 + HW;
        bC0 = bb0[Bt.i00]; bC1 = bb0[Bt.i01]; bC2 = bb0[Bt.i10]; bC3 = bb0[Bt.i11];
        bC4 = bb1[Bt.i00]; bC5 = bb1[Bt.i01]; bC6 = bb1[Bt.i10]; bC7 = bb1[Bt.i11];
        fCx = fNx; fCy = fNy;
      }
      if (s <= SS - 7) {                       // issue static f(s+5)
        const float* fp_ = ff + (size_t)(s + 5) * 2 * HW;
        fNx = fp_[pp]; fNy = fp_[HW + pp];
      }
    }
    // SWAR: byte c of cv[r] is cell 8j+c; free = byte != tag -> bit c.
    {
      unsigned char* nb = (unsigned char*)wds;
      const unsigned long long tr = 0x0101010101010101ull * (unsigned long long)tag;
      int t = threadIdx.x;
#pragma unroll
      for (int r = 0; r < 16; ++r) {
        int j = t + 256 * r;
        unsigned long long xx = cv[r] ^ tr;
        unsigned long long t1 = (xx & 0x7F7F7F7F7F7F7F7Full) + 0x7F7F7F7F7F7F7F7Full;
        unsigned long long nz = ((t1 | xx) >> 7) & 0x0101010101010101ull;
        unsigned char byte = (unsigned char)((nz * 0x0102040810204080ull) >> 56);
        nb[j] = (j < GG / 8) ? byte : (unsigned char)0;   // pads zero
      }
    }
    __syncthreads();
    // Popcount prefix over the bitmap (shuffle scan, as verified).
    {
      int t = threadIdx.x;
      int e0 = 2 * t, e1 = 2 * t + 1;
      unsigned long long m0 = wds[e0];
      unsigned long long m1 = wds[e1];
      int p0 = __popcll(m0), p1 = __popcll(m1);
      int v = p0 + p1;
      for (int o = 1; o < 64; o <<= 1) {
        int uu = __shfl_up(v, o, 64);
        if (lane >= o) v += uu;
      }
      if (lane == 63) wsum[wv] = v;
      __syncthreads();
      int base = 0;
      for (int j2 = 0; j2 < wv; ++j2) base += wsum[j2];
      pref[e0] = (unsigned int)(base + v - p1);
      pref[e1] = (unsigned int)(base + v);
      __syncthreads();
    }
    int tc = (int)pref[CWP - 1];              // total free candidates

    if (st < 0.0f) {
      int r = ps + (int)__popcll(smask & ltmask);
      if (r < tc) {                  // r < min(num_cand, num_free) <=> r < num_cand
        // word k containing rank r: largest k with pref[k-1] <= r
        int k = 0;
        for (int bb = 256; bb >= 1; bb >>= 1) {
          int nk = k + bb;
          if (nk <= CWP - 1 && (int)pref[nk - 1] <= r) k = nk;
        }
        int j = r - (k ? (int)pref[k - 1] : 0);
        unsigned long long m = wds[k];
        int lo = 0;                  // position of the (j+1)-th set bit
        for (int bb = 32; bb >= 1; bb >>= 1) {
          int nb2 = lo + bb;
          unsigned long long mask = (nb2 >= 64) ? ~0ull : ((1ull << nb2) - 1ull);
          if (__popcll(m & mask) <= j) lo = nb2;
        }
        int g = k * 64 + lo;
        int ii = g / GXC, jj = g - ii * GXC;
        x = (float)(MARGIN + STEP * jj);
        y = (float)(MARGIN + STEP * ii);
        st = (float)(s + 1);
        mode = 2;
        if (s < SS - 2)              // at s=30 there is no A(31): skip the load
          pa64 = aload64(&intadv[(size_t)(s + 1) * GG + g]);   // in flight to A(s+1)
      }
    }
    X[(size_t)(s + 1) * NSLOT + slot] = x;
    Y[(size_t)(s + 1) * NSLOT + slot] = y;
    // no trailing __syncthreads: wcnt is parity-double-buffered, and wds/pref
    // rewrites happen only after the next barrier_ps4's entry __syncthreads.
  }

#undef ISSUE_TAP
#undef PRUNE_TAP

  Start[slot] = st;
}

// ---------------------------------------------------------------------------
extern "C" void kernel_launch(void* const* d_in, const int* in_sizes, int n_in,
                              void* d_out, int out_size, void* d_ws, size_t ws_size,
                              hipStream_t stream) {
  const float* ff  = (const float*)d_in[0];   // (1,S,2,H,W)
  const float* fbk = (const float*)d_in[1];

  float* X     = (float*)d_out;                       // (S, N)
  float* Y     = X + (size_t)SS * NSLOT;              // (S, N)
  float* Start = Y + (size_t)SS * NSLOT;              // (N,)

  unsigned long long* flags  = (unsigned long long*)d_ws;             // 128 KB
  unsigned char*      occ    = (unsigned char*)(flags + 2 * FP8);     // 2 planes
  unsigned long long* intadv = (unsigned long long*)(occ + 2 * OCCB); // 31*GG u64

  k_init<<<58, 256, 0, stream>>>(flags, (unsigned int*)occ);

  k_steps<<<NBLK, 256, 0, stream>>>(ff, fbk, X, Y, Start, occ, flags, intadv);
}

// Round 7
// 417.545 us; speedup vs baseline: 3.2938x; 1.0265x over previous
//
#include <hip/hip_runtime.h>
#include <cstdint>

// Problem constants (fixed by setup_inputs: H=480, W=1024, S=32, margin=10, step=4)
#define HH 480
#define WW 1024
#define SS 32
#define HW (HH*WW)              // 491520
#define MARGIN 10
#define STEP 4
#define GYC 116                 // len(arange(10, 471, 4))
#define GXC 252                 // len(arange(10, 1015, 4))
#define GG (GYC*GXC)            // 29232 grid candidates (= 456*64 + 48)
#define NSLOT (2*HH*WW/(STEP*STEP))  // 61440 trajectory slots
#define NBLK (NSLOT/256)        // 240 blocks -> co-resident on 256 CUs
#define NWAVE (NSLOT/64)        // 960 waves
#define CW ((GG+63)/64)         // 457 candidate bitmap words
#define CWP 512                 // padded word count (per-block scan width)
#define OCCB (CW*64)            // 29248 bytes per occupancy plane
#define FPW 256                 // u64 entries per parity plane (PACKED: 8 lines)
#define CPB 122                 // producer cells per block (240*122 >= GG)

// Agent-scope (device-coherent) accessors.
__device__ __forceinline__ unsigned int aload(const unsigned int* p) {
  return __hip_atomic_load(p, __ATOMIC_RELAXED, __HIP_MEMORY_SCOPE_AGENT);
}
__device__ __forceinline__ void astore(unsigned int* p, unsigned int v) {
  __hip_atomic_store(p, v, __ATOMIC_RELAXED, __HIP_MEMORY_SCOPE_AGENT);
}
__device__ __forceinline__ unsigned long long aload64(const unsigned long long* p) {
  return __hip_atomic_load(p, __ATOMIC_RELAXED, __HIP_MEMORY_SCOPE_AGENT);
}
__device__ __forceinline__ void astore64(unsigned long long* p, unsigned long long v) {
  __hip_atomic_store(p, v, __ATOMIC_RELAXED, __HIP_MEMORY_SCOPE_AGENT);
}
__device__ __forceinline__ void astore8(unsigned char* p, unsigned char v) {
  __hip_atomic_store(p, v, __ATOMIC_RELAXED, __HIP_MEMORY_SCOPE_AGENT);
}

__device__ __forceinline__ int clampi(int v, int lo, int hi) {
  return v < lo ? lo : (v > hi ? hi : v);
}

// ---------------------------------------------------------------------------
// K0: zero BOTH occupancy tag planes + init both parity flag planes.
// Flags are PACKED: 256 u64 per plane = 8 cache lines (was 256 lines) ->
// the poll's coherence traffic drops 32x. Stores hit distinct 8B entries
// (byte-granular merge at the coherence point; no RMW, no lost updates).
// ---------------------------------------------------------------------------
__global__ __launch_bounds__(256) void k_init(unsigned long long* __restrict__ flags,
                                              unsigned int* __restrict__ occ32)
{
  int idx = blockIdx.x * 256 + threadIdx.x;
  if (idx < (2 * OCCB / 4)) occ32[idx] = 0u;         // 14624 words = 2 planes
  if (idx < 256) {
    unsigned long long v = (idx < NBLK) ? 0ull : (0x7FFFFFFFull << 32); // pads: +inf
    flags[idx] = v;
    flags[FPW + idx] = v;
  }
}

// ---------------------------------------------------------------------------
// Bilinear footprint at (xs,ys). Identical float ops to the verified kernels.
// ---------------------------------------------------------------------------
struct Bil {
  int x0i, x1i, y0i, y1i;
  int i00, i01, i10, i11;
  float w00, w01, w10, w11;
};

__device__ __forceinline__ Bil mkbil(float xs, float ys) {
#pragma clang fp contract(off)
  float x0 = floorf(xs), y0 = floorf(ys);
  float wx1 = xs - x0, wx0 = 1.0f - wx1;
  float wy1 = ys - y0, wy0 = 1.0f - wy1;
  Bil b;
  b.x0i = clampi((int)x0, 0, WW - 1);
  b.x1i = b.x0i + 1 > WW - 1 ? WW - 1 : b.x0i + 1;
  b.y0i = clampi((int)y0, 0, HH - 1);
  b.y1i = b.y0i + 1 > HH - 1 ? HH - 1 : b.y0i + 1;
  b.i00 = b.y0i * WW + b.x0i; b.i01 = b.y0i * WW + b.x1i;
  b.i10 = b.y1i * WW + b.x0i; b.i11 = b.y1i * WW + b.x1i;
  b.w00 = wy0 * wx0; b.w01 = wy0 * wx1;
  b.w10 = wy1 * wx0; b.w11 = wy1 * wx1;
  return b;
}

// Fwd-bwd consistency bit from pre-gathered backward-flow corner values.
__device__ __forceinline__ float prune_val(float fx, float fy,
    float c00a, float c01a, float c10a, float c11a,
    float c00b, float c01b, float c10b, float c11b, const Bil& t)
{
#pragma clang fp contract(off)
  float bw0 = ((c00a * t.w00 + c01a * t.w01) + c10a * t.w10) + c11a * t.w11;
  float bw1 = ((c00b * t.w00 + c01b * t.w01) + c10b * t.w10) + c11b * t.w11;
  float t0 = fx + bw0, t1 = fy + bw1;
  float diff = sqrtf(t0 * t0 + t1 * t1);
  float magf = sqrtf(fx * fx + fy * fy);
  float magb = sqrtf(bw0 * bw0 + bw1 * bw1);
  float mag = 0.5f * (magf + magb);
  return (diff <= 0.01f * mag + 0.1f) ? 1.0f : 0.0f;
}

// Integer-cell first-transition outcome {xt,yt,choose} packed as u64
// (choose encoded as yt<0). Bit-identical to the verified mode-2 path.
__device__ __forceinline__ unsigned long long make_intadv(
    int pix, int piy, float fx, float fy, const float* __restrict__ bks)
{
#pragma clang fp contract(off)
  float xt = (float)pix + fx, yt = (float)piy + fy;
  Bil Bt = mkbil(xt, yt);
  const float* b0p = bks;
  const float* b1p = bks + HW;
  float o = prune_val(fx, fy,
                      b0p[Bt.i00], b0p[Bt.i01], b0p[Bt.i10], b0p[Bt.i11],
                      b1p[Bt.i00], b1p[Bt.i01], b1p[Bt.i10], b1p[Bt.i11], Bt);
  bool marg = (xt > (float)MARGIN) && (yt > (float)MARGIN) &&
              (xt < (float)(WW - MARGIN)) && (yt < (float)(HH - MARGIN));
  bool ch = marg && (o > 0.5f);
  unsigned lo = __float_as_uint(ch ? xt : 0.0f);
  unsigned hi = __float_as_uint(ch ? yt : -1.0f);
  return ((unsigned long long)hi << 32) | (unsigned long long)lo;
}

// ---------------------------------------------------------------------------
// K1: persistent scan, ONE grid barrier per step. Round-7 changes (work is
// byte-identical; only flag layout + intra-step scheduling move):
//  * PACKED FLAGS (see k_init): poll coherence traffic /32.
//  * SPLIT BARRIER WITH FILLED WAIT WINDOW: entry __syncthreads (drains
//    marks) -> arrival store -> ALL barrier-independent work (consumer
//    advect + 32 b-tap issues; producer intadv publish + b/f issues) ->
//    wave-0 poll -> exit __syncthreads -> compression/scan/births.
//    The issue work rides inside the barrier wait instead of after it.
//    Visibility unchanged: intadv published at step s is consumed at step
//    s+2 (two barrier-entry vmcnt drains later); pb taps are consumed at
//    A(s+1) under compiler waitcnt.
// ---------------------------------------------------------------------------
__global__ __launch_bounds__(256, 1) void k_steps(
    const float* __restrict__ ff, const float* __restrict__ fbk,
    float* __restrict__ X, float* __restrict__ Y, float* __restrict__ Start,
    unsigned char* __restrict__ occ, unsigned long long* __restrict__ flags,
    unsigned long long* __restrict__ intadv)
{
#pragma clang fp contract(off)
  const int b = blockIdx.x;
  const int lane = threadIdx.x & 63;
  const int wv = threadIdx.x >> 6;                   // wave-in-block 0..3
  const int slot = ((wv * NBLK + b) << 6) | lane;    // wave-permuted slot id
  const unsigned long long ltmask = (1ull << lane) - 1ull;

  __shared__ unsigned long long wds[CWP];   // free-candidate bitmap (4 KB)
  __shared__ unsigned int pref[CWP];        // inclusive popcount prefix (2 KB)
  __shared__ int wsum[4];                   // scan partials
  __shared__ int wcnt[2][4];                // per-wave dead counts (parity)
  __shared__ int ps4[4];                    // per-wave lower-rank totals

  // Consumer slot state. mode: 0 dead, 1 pipelined, 2 integer-pos (pa64 valid).
  float x = 0.f, y = 0.f, st = -1.f;
  int mode = 0;
  float pf0 = 0.f, pf1 = 0.f, pf2 = 0.f, pf3 = 0.f;   // f0 at taps 00,01,10,11
  float pf4 = 0.f, pf5 = 0.f, pf6 = 0.f, pf7 = 0.f;   // f1 at taps 00,01,10,11
  float pb[32];                                        // b corner values, 8/tap
  float pxt = 0.f, pyt = 0.f;                          // advected candidate
  bool  pmarg = false;
  unsigned long long pa64 = (unsigned long long)0xBF800000u << 32;  // yt=-1

  // Producer identity (decoupled from slot): even threads, ~30 cells/wave.
  const int pj = threadIdx.x >> 1;
  const int pcell = b * CPB + pj;
  const bool prod = ((threadIdx.x & 1) == 0) && (pj < CPB) && (pcell < GG);
  int pix = 0, piy = 0, pp = 0;
  float fNx = 0.f, fNy = 0.f;      // f(s+4) pair (issued last step)
  float fCx = 0.f, fCy = 0.f;      // f(s+3) pair (arrived)
  float bC0 = 0.f, bC1 = 0.f, bC2 = 0.f, bC3 = 0.f;   // b(s+3) corners
  float bC4 = 0.f, bC5 = 0.f, bC6 = 0.f, bC7 = 0.f;

  // ---- Slot prologue: initial alive slots compute their own A(0) input ----
  if (slot < GG) {
    int ii = slot / GXC, jj = slot - ii * GXC;
    int ix = MARGIN + STEP * jj, iy = MARGIN + STEP * ii;
    x = (float)ix; y = (float)iy;
    st = 0.f; mode = 2;
    int p0_ = iy * WW + ix;
    float f0x = ff[p0_], f0y = ff[HW + p0_];
    pa64 = make_intadv(ix, iy, f0x, f0y, fbk);
  }
  X[slot] = x; Y[slot] = y;   // row 0

  // ---- Producer prologue: bootstrap intadv[1..2] + b(3)/f(4) in flight ----
  if (prod) {
    int ii = pcell / GXC, jj = pcell - ii * GXC;
    pix = MARGIN + STEP * jj; piy = MARGIN + STEP * ii;
    pp = piy * WW + pix;
    float f1x = ff[(size_t)1 * 2 * HW + pp], f1y = ff[(size_t)1 * 2 * HW + HW + pp];
    float f2x = ff[(size_t)2 * 2 * HW + pp], f2y = ff[(size_t)2 * 2 * HW + HW + pp];
    float f3x = ff[(size_t)3 * 2 * HW + pp], f3y = ff[(size_t)3 * 2 * HW + HW + pp];
    fNx = ff[(size_t)4 * 2 * HW + pp];       fNy = ff[(size_t)4 * 2 * HW + HW + pp];
    astore64(&intadv[(size_t)1 * GG + pcell],
             make_intadv(pix, piy, f1x, f1y, fbk + (size_t)1 * 2 * HW));
    astore64(&intadv[(size_t)2 * GG + pcell],
             make_intadv(pix, piy, f2x, f2y, fbk + (size_t)2 * 2 * HW));
    {  // issue b(3) corners; consumed at overlap(0)
      float xt = (float)pix + f3x, yt = (float)piy + f3y;
      Bil Bt = mkbil(xt, yt);
      const float* bb0 = fbk + (size_t)3 * 2 * HW;
      const float* bb1 = bb0 + HW;
      bC0 = bb0[Bt.i00]; bC1 = bb0[Bt.i01]; bC2 = bb0[Bt.i10]; bC3 = bb0[Bt.i11];
      bC4 = bb1[Bt.i00]; bC5 = bb1[Bt.i01]; bC6 = bb1[Bt.i10]; bC7 = bb1[Bt.i11];
      fCx = f3x; fCy = f3y;
    }
  }

// Issue the 32 b-corner loads for tap tt (consumed next iteration's A).
#define ISSUE_TAP(tt, TXI, TYI, FX, FY) do { \
    Bil Bt = mkbil((float)P.TXI + (FX), (float)P.TYI + (FY)); \
    pb[(tt)*8+0] = b0n[Bt.i00]; pb[(tt)*8+1] = b0n[Bt.i01]; \
    pb[(tt)*8+2] = b0n[Bt.i10]; pb[(tt)*8+3] = b0n[Bt.i11]; \
    pb[(tt)*8+4] = b1n[Bt.i00]; pb[(tt)*8+5] = b1n[Bt.i01]; \
    pb[(tt)*8+6] = b1n[Bt.i10]; pb[(tt)*8+7] = b1n[Bt.i11]; \
  } while (0)

// Recompute the identical footprint and fold pre-loaded values into the bit.
#define PRUNE_TAP(tt, TXI, TYI, FX, FY, OUT) do { \
    Bil Bt = mkbil((float)P.TXI + (FX), (float)P.TYI + (FY)); \
    OUT = prune_val((FX), (FY), \
                    pb[(tt)*8+0], pb[(tt)*8+1], pb[(tt)*8+2], pb[(tt)*8+3], \
                    pb[(tt)*8+4], pb[(tt)*8+5], pb[(tt)*8+6], pb[(tt)*8+7], Bt); \
  } while (0)

  for (int s = 0; s < SS - 1; ++s) {
    const float* f0n = ff + (size_t)(s + 1) * 2 * HW;  // NEXT step's fwd flow
    const float* f1n = f0n + HW;
    const unsigned char tag = (unsigned char)(s + 1);
    unsigned char* occw = occ + (((s + 1) & 1) ? OCCB : 0);   // this step's plane

    // ---- Phase A: prune decision (pure VALU) + occ tag marks --------------
    bool moved = false;
    if (mode == 1) {
      Bil P = mkbil(x, y);
      float o0, o1, o2, o3;
      PRUNE_TAP(0, x0i, y0i, pf0, pf4, o0);
      PRUNE_TAP(1, x1i, y0i, pf1, pf5, o1);
      PRUNE_TAP(2, x0i, y1i, pf2, pf6, o2);
      PRUNE_TAP(3, x1i, y1i, pf3, pf7, o3);
      float fbv = ((o0 * P.w00 + o1 * P.w01) + o2 * P.w10) + o3 * P.w11;
      if (pmarg && fbv > 0.5f) {
        x = pxt; y = pyt;
        Bil Pn = mkbil(x, y);                 // prefetch f for step s+1
        pf0 = f0n[Pn.i00]; pf1 = f0n[Pn.i01]; pf2 = f0n[Pn.i10]; pf3 = f0n[Pn.i11];
        pf4 = f1n[Pn.i00]; pf5 = f1n[Pn.i01]; pf6 = f1n[Pn.i10]; pf7 = f1n[Pn.i11];
        moved = true;
      } else { st = -1.f; x = 0.f; y = 0.f; mode = 0; }
    } else if (mode == 2) {
      // Integer position: precomputed outcome (pre-issued 8B load).
      float axt = __uint_as_float((unsigned)pa64);
      float ayt = __uint_as_float((unsigned)(pa64 >> 32));
      if (ayt >= 0.0f) {                      // choose
        x = axt; y = ayt; mode = 1;
        Bil Pn = mkbil(x, y);                 // prefetch f for step s+1
        pf0 = f0n[Pn.i00]; pf1 = f0n[Pn.i01]; pf2 = f0n[Pn.i10]; pf3 = f0n[Pn.i11];
        pf4 = f1n[Pn.i00]; pf5 = f1n[Pn.i01]; pf6 = f1n[Pn.i10]; pf7 = f1n[Pn.i11];
        moved = true;
      } else { st = -1.f; x = 0.f; y = 0.f; mode = 0; }
    }
    if (moved) {
      int oy = (int)y, ox = (int)x;   // trunc == floor (positive)
      int i0 = ((oy - (MARGIN + 2) + 4099) >> 2) - 1024;  // ceil((oy-12)/4)
      int i1 = ((oy - (MARGIN - 2) + 4096) >> 2) - 1024;  // floor((oy-8)/4)
      int j0 = ((ox - (MARGIN + 2) + 4099) >> 2) - 1024;
      int j1 = ((ox - (MARGIN - 2) + 4096) >> 2) - 1024;
      if (i0 < 0) i0 = 0; if (i1 > GYC - 1) i1 = GYC - 1;
      if (j0 < 0) j0 = 0; if (j1 > GXC - 1) j1 = GXC - 1;
      for (int i = i0; i <= i1; ++i)
        for (int j = j0; j <= j1; ++j)
          astore8(&occw[i * GXC + j], tag);   // same-value stores: benign race
    }
    unsigned long long smask = __ballot(st < 0.0f);
    if (lane == 0) wcnt[s & 1][wv] = (int)__popcll(smask);

    // ---- Barrier arrival: entry sync drains ALL marks, then one store ----
    unsigned long long* fb = flags + (s & 1) * FPW;
    const int epoch = s + 1;
    __syncthreads();
    if (threadIdx.x == 0) {
      const int* wc = wcnt[s & 1];
      unsigned cpack = (unsigned)wc[0] | ((unsigned)wc[1] << 8)
                     | ((unsigned)wc[2] << 16) | ((unsigned)wc[3] << 24);
      astore64(&fb[b],
               ((unsigned long long)(unsigned)epoch << 32) | (unsigned long long)cpack);
    }

    // ---- Wait-window overlap: all barrier-independent issue work ---------
    // Consumer: advect + issue 32 b(s+1) loads (consumed at A(s+1)).
    if (mode == 1 && s < SS - 2) {
      Bil P = mkbil(x, y);
      float u_ = ((pf0 * P.w00 + pf1 * P.w01) + pf2 * P.w10) + pf3 * P.w11;
      float v_ = ((pf4 * P.w00 + pf5 * P.w01) + pf6 * P.w10) + pf7 * P.w11;
      pxt = x + u_; pyt = y + v_;
      pmarg = (pxt > (float)MARGIN) && (pyt > (float)MARGIN) &&
              (pxt < (float)(WW - MARGIN)) && (pyt < (float)(HH - MARGIN));
      const float* b0n = fbk + (size_t)(s + 1) * 2 * HW;
      const float* b1n = b0n + HW;
      ISSUE_TAP(0, x0i, y0i, pf0, pf4);
      ISSUE_TAP(1, x1i, y0i, pf1, pf5);
      ISSUE_TAP(2, x0i, y1i, pf2, pf6);
      ISSUE_TAP(3, x1i, y1i, pf3, pf7);
    }
    // Producer: compute+publish intadv[s+3]; issue b(s+4); issue f(s+5).
    if (prod) {
      if (s <= SS - 5) {                       // k = s+3 <= 30
        float xt = (float)pix + fCx, yt = (float)piy + fCy;
        Bil Bt = mkbil(xt, yt);
        float o = prune_val(fCx, fCy, bC0, bC1, bC2, bC3, bC4, bC5, bC6, bC7, Bt);
        bool marg = (xt > (float)MARGIN) && (yt > (float)MARGIN) &&
                    (xt < (float)(WW - MARGIN)) && (yt < (float)(HH - MARGIN));
        bool ch = marg && (o > 0.5f);
        unsigned lo = __float_as_uint(ch ? xt : 0.0f);
        unsigned hi = __float_as_uint(ch ? yt : -1.0f);
        astore64(&intadv[(size_t)(s + 3) * GG + pcell],
                 ((unsigned long long)hi << 32) | (unsigned long long)lo);
      }
      if (s <= SS - 6) {                       // issue b(s+4), f(s+4) arrived
        float xt = (float)pix + fNx, yt = (float)piy + fNy;
        Bil Bt = mkbil(xt, yt);
        const float* bb0 = fbk + (size_t)(s + 4) * 2 * HW;
        const float* bb1 = bb0 + HW;
        bC0 = bb0[Bt.i00]; bC1 = bb0[Bt.i01]; bC2 = bb0[Bt.i10]; bC3 = bb0[Bt.i11];
        bC4 = bb1[Bt.i00]; bC5 = bb1[Bt.i01]; bC6 = bb1[Bt.i10]; bC7 = bb1[Bt.i11];
        fCx = fNx; fCy = fNy;
      }
      if (s <= SS - 7) {                       // issue static f(s+5)
        const float* fp_ = ff + (size_t)(s + 5) * 2 * HW;
        fNx = fp_[pp]; fNy = fp_[HW + pp];
      }
    }

    // ---- Poll (wave 0): 4 loads/lane over 8 packed lines + rank prefix ---
    if (threadIdx.x < 64) {
      unsigned long long v0, v1, v2, v3;
      for (;;) {
        v0 = aload64(&fb[lane      ]);
        v1 = aload64(&fb[lane +  64]);
        v2 = aload64(&fb[lane + 128]);
        v3 = aload64(&fb[lane + 192]);
        unsigned m0 = (unsigned)(v0 >> 32), m1 = (unsigned)(v1 >> 32);
        unsigned m2 = (unsigned)(v2 >> 32), m3 = (unsigned)(v3 >> 32);
        unsigned mn = m0 < m1 ? m0 : m1;
        unsigned mn2 = m2 < m3 ? m2 : m3;
        mn = mn < mn2 ? mn : mn2;
        for (int o = 32; o > 0; o >>= 1) {
          unsigned t = (unsigned)__shfl_xor((int)mn, o, 64);
          mn = mn < t ? mn : t;
        }
        if ((int)mn >= epoch) break;
        __builtin_amdgcn_s_sleep(1);
      }
      // unpack 4x8 -> 4x16 packed u64 (field sums <= 240*64 = 15360 < 65536)
      auto up = [](unsigned long long f) -> unsigned long long {
        unsigned c = (unsigned)f;
        return (unsigned long long)(c & 0xFFu)
             | ((unsigned long long)((c >>  8) & 0xFFu) << 16)
             | ((unsigned long long)((c >> 16) & 0xFFu) << 32)
             | ((unsigned long long)((c >> 24) & 0xFFu) << 48);
      };
      unsigned long long u0 = up(v0), u1 = up(v1), u2 = up(v2), u3 = up(v3);
      unsigned long long F = u0 + u1 + u2 + u3;
      unsigned long long Pp = (lane       < b ? u0 : 0ull)
                            + (lane +  64 < b ? u1 : 0ull)
                            + (lane + 128 < b ? u2 : 0ull)
                            + (lane + 192 < b ? u3 : 0ull);
      for (int o = 32; o > 0; o >>= 1) {
        unsigned flo = (unsigned)F, fhi = (unsigned)(F >> 32);
        unsigned plo = (unsigned)Pp, phi = (unsigned)(Pp >> 32);
        unsigned flo2 = (unsigned)__shfl_xor((int)flo, o, 64);
        unsigned fhi2 = (unsigned)__shfl_xor((int)fhi, o, 64);
        unsigned plo2 = (unsigned)__shfl_xor((int)plo, o, 64);
        unsigned phi2 = (unsigned)__shfl_xor((int)phi, o, 64);
        F  += ((unsigned long long)fhi2 << 32) | flo2;
        Pp += ((unsigned long long)phi2 << 32) | plo2;
      }
      if (lane == 0) {
        int f0 = (int)(F & 0xFFFF), f1 = (int)((F >> 16) & 0xFFFF), f2 = (int)((F >> 32) & 0xFFFF);
        int p0 = (int)(Pp & 0xFFFF), p1 = (int)((Pp >> 16) & 0xFFFF);
        int p2 = (int)((Pp >> 32) & 0xFFFF), p3 = (int)((Pp >> 48) & 0xFFFF);
        ps4[0] = p0;
        ps4[1] = f0 + p1;
        ps4[2] = f0 + f1 + p2;
        ps4[3] = f0 + f1 + f2 + p3;
      }
    }
    __syncthreads();
    int ps = ps4[wv];

    // ---- Phase CD: compression, scan, births -----------------------------
    // Compression: 15 independent coalesced u64 agent loads (one exposure).
    unsigned long long cv[16];
    {
      const unsigned long long* occ64 =
          (const unsigned long long*)(occ + (((s + 1) & 1) ? OCCB : 0));
      int t = threadIdx.x;
#pragma unroll
      for (int r = 0; r < 16; ++r) {
        int j = t + 256 * r;
        cv[r] = (j < GG / 8) ? aload64(&occ64[j]) : 0ull;   // GG/8 = 3654
      }
    }
    // SWAR: byte c of cv[r] is cell 8j+c; free = byte != tag -> bit c.
    {
      unsigned char* nb = (unsigned char*)wds;
      const unsigned long long tr = 0x0101010101010101ull * (unsigned long long)tag;
      int t = threadIdx.x;
#pragma unroll
      for (int r = 0; r < 16; ++r) {
        int j = t + 256 * r;
        unsigned long long xx = cv[r] ^ tr;
        unsigned long long t1 = (xx & 0x7F7F7F7F7F7F7F7Full) + 0x7F7F7F7F7F7F7F7Full;
        unsigned long long nz = ((t1 | xx) >> 7) & 0x0101010101010101ull;
        unsigned char byte = (unsigned char)((nz * 0x0102040810204080ull) >> 56);
        nb[j] = (j < GG / 8) ? byte : (unsigned char)0;   // pads zero
      }
    }
    __syncthreads();
    // Popcount prefix over the bitmap (shuffle scan, as verified).
    {
      int t = threadIdx.x;
      int e0 = 2 * t, e1 = 2 * t + 1;
      unsigned long long m0 = wds[e0];
      unsigned long long m1 = wds[e1];
      int p0 = __popcll(m0), p1 = __popcll(m1);
      int v = p0 + p1;
      for (int o = 1; o < 64; o <<= 1) {
        int uu = __shfl_up(v, o, 64);
        if (lane >= o) v += uu;
      }
      if (lane == 63) wsum[wv] = v;
      __syncthreads();
      int base = 0;
      for (int j2 = 0; j2 < wv; ++j2) base += wsum[j2];
      pref[e0] = (unsigned int)(base + v - p1);
      pref[e1] = (unsigned int)(base + v);
      __syncthreads();
    }
    int tc = (int)pref[CWP - 1];              // total free candidates

    if (st < 0.0f) {
      int r = ps + (int)__popcll(smask & ltmask);
      if (r < tc) {                  // r < min(num_cand, num_free) <=> r < num_cand
        // word k containing rank r: largest k with pref[k-1] <= r
        int k = 0;
        for (int bb = 256; bb >= 1; bb >>= 1) {
          int nk = k + bb;
          if (nk <= CWP - 1 && (int)pref[nk - 1] <= r) k = nk;
        }
        int j = r - (k ? (int)pref[k - 1] : 0);
        unsigned long long m = wds[k];
        int lo = 0;                  // position of the (j+1)-th set bit
        for (int bb = 32; bb >= 1; bb >>= 1) {
          int nb2 = lo + bb;
          unsigned long long mask = (nb2 >= 64) ? ~0ull : ((1ull << nb2) - 1ull);
          if (__popcll(m & mask) <= j) lo = nb2;
        }
        int g = k * 64 + lo;
        int ii = g / GXC, jj = g - ii * GXC;
        x = (float)(MARGIN + STEP * jj);
        y = (float)(MARGIN + STEP * ii);
        st = (float)(s + 1);
        mode = 2;
        if (s < SS - 2)              // at s=30 there is no A(31): skip the load
          pa64 = aload64(&intadv[(size_t)(s + 1) * GG + g]);   // in flight to A(s+1)
      }
    }
    X[(size_t)(s + 1) * NSLOT + slot] = x;
    Y[(size_t)(s + 1) * NSLOT + slot] = y;
    // no trailing __syncthreads: wcnt is parity-double-buffered, and wds/pref
    // rewrites happen only after the next step's post-poll __syncthreads.
  }

#undef ISSUE_TAP
#undef PRUNE_TAP

  Start[slot] = st;
}

// ---------------------------------------------------------------------------
extern "C" void kernel_launch(void* const* d_in, const int* in_sizes, int n_in,
                              void* d_out, int out_size, void* d_ws, size_t ws_size,
                              hipStream_t stream) {
  const float* ff  = (const float*)d_in[0];   // (1,S,2,H,W)
  const float* fbk = (const float*)d_in[1];

  float* X     = (float*)d_out;                       // (S, N)
  float* Y     = X + (size_t)SS * NSLOT;              // (S, N)
  float* Start = Y + (size_t)SS * NSLOT;              // (N,)

  unsigned long long* flags  = (unsigned long long*)d_ws;             // 4 KB
  unsigned char*      occ    = (unsigned char*)(flags + 2 * FPW);     // 2 planes
  unsigned long long* intadv = (unsigned long long*)(occ + 2 * OCCB); // 31*GG u64

  k_init<<<58, 256, 0, stream>>>(flags, (unsigned int*)occ);

  k_steps<<<NBLK, 256, 0, stream>>>(ff, fbk, X, Y, Start, occ, flags, intadv);
}

// Round 9
// 413.675 us; speedup vs baseline: 3.3246x; 1.0094x over previous
//
#include <hip/hip_runtime.h>
#include <cstdint>

// Problem constants (fixed by setup_inputs: H=480, W=1024, S=32, margin=10, step=4)
#define HH 480
#define WW 1024
#define SS 32
#define HW (HH*WW)              // 491520
#define MARGIN 10
#define STEP 4
#define GYC 116                 // len(arange(10, 471, 4))
#define GXC 252                 // len(arange(10, 1015, 4))
#define GG (GYC*GXC)            // 29232 grid candidates (= 456*64 + 48)
#define NSLOT (2*HH*WW/(STEP*STEP))  // 61440 trajectory slots
#define NBLK (NSLOT/256)        // 240 blocks -> co-resident on 256 CUs
#define NWAVE (NSLOT/64)        // 960 waves
#define CW ((GG+63)/64)         // 457 candidate bitmap words
#define CWP 512                 // padded word count (per-block scan width)
#define OCCB (CW*64)            // 29248 bytes per occupancy plane
#define FPW 256                 // u64 entries per parity plane (PACKED: 8 lines)
#define CPB 122                 // producer cells per block (240*122 >= GG)

// Agent-scope (device-coherent) accessors.
__device__ __forceinline__ unsigned int aload(const unsigned int* p) {
  return __hip_atomic_load(p, __ATOMIC_RELAXED, __HIP_MEMORY_SCOPE_AGENT);
}
__device__ __forceinline__ void astore(unsigned int* p, unsigned int v) {
  __hip_atomic_store(p, v, __ATOMIC_RELAXED, __HIP_MEMORY_SCOPE_AGENT);
}
__device__ __forceinline__ unsigned long long aload64(const unsigned long long* p) {
  return __hip_atomic_load(p, __ATOMIC_RELAXED, __HIP_MEMORY_SCOPE_AGENT);
}
__device__ __forceinline__ void astore64(unsigned long long* p, unsigned long long v) {
  __hip_atomic_store(p, v, __ATOMIC_RELAXED, __HIP_MEMORY_SCOPE_AGENT);
}
__device__ __forceinline__ void astore8(unsigned char* p, unsigned char v) {
  __hip_atomic_store(p, v, __ATOMIC_RELAXED, __HIP_MEMORY_SCOPE_AGENT);
}

__device__ __forceinline__ int clampi(int v, int lo, int hi) {
  return v < lo ? lo : (v > hi ? hi : v);
}

// ---------------------------------------------------------------------------
// K0: zero BOTH occupancy tag planes + init both parity flag planes.
// Flags are PACKED: 256 u64 per plane = 8 cache lines.
// ---------------------------------------------------------------------------
__global__ __launch_bounds__(256) void k_init(unsigned long long* __restrict__ flags,
                                              unsigned int* __restrict__ occ32)
{
  int idx = blockIdx.x * 256 + threadIdx.x;
  if (idx < (2 * OCCB / 4)) occ32[idx] = 0u;         // 14624 words = 2 planes
  if (idx < 256) {
    unsigned long long v = (idx < NBLK) ? 0ull : (0x7FFFFFFFull << 32); // pads: +inf
    flags[idx] = v;
    flags[FPW + idx] = v;
  }
}

// ---------------------------------------------------------------------------
// Bilinear footprint at (xs,ys). Identical float ops to the verified kernels.
// ---------------------------------------------------------------------------
struct Bil {
  int x0i, x1i, y0i, y1i;
  int i00, i01, i10, i11;
  float w00, w01, w10, w11;
};

__device__ __forceinline__ Bil mkbil(float xs, float ys) {
#pragma clang fp contract(off)
  float x0 = floorf(xs), y0 = floorf(ys);
  float wx1 = xs - x0, wx0 = 1.0f - wx1;
  float wy1 = ys - y0, wy0 = 1.0f - wy1;
  Bil b;
  b.x0i = clampi((int)x0, 0, WW - 1);
  b.x1i = b.x0i + 1 > WW - 1 ? WW - 1 : b.x0i + 1;
  b.y0i = clampi((int)y0, 0, HH - 1);
  b.y1i = b.y0i + 1 > HH - 1 ? HH - 1 : b.y0i + 1;
  b.i00 = b.y0i * WW + b.x0i; b.i01 = b.y0i * WW + b.x1i;
  b.i10 = b.y1i * WW + b.x0i; b.i11 = b.y1i * WW + b.x1i;
  b.w00 = wy0 * wx0; b.w01 = wy0 * wx1;
  b.w10 = wy1 * wx0; b.w11 = wy1 * wx1;
  return b;
}

// Fwd-bwd consistency bit from pre-gathered backward-flow corner values.
__device__ __forceinline__ float prune_val(float fx, float fy,
    float c00a, float c01a, float c10a, float c11a,
    float c00b, float c01b, float c10b, float c11b, const Bil& t)
{
#pragma clang fp contract(off)
  float bw0 = ((c00a * t.w00 + c01a * t.w01) + c10a * t.w10) + c11a * t.w11;
  float bw1 = ((c00b * t.w00 + c01b * t.w01) + c10b * t.w10) + c11b * t.w11;
  float t0 = fx + bw0, t1 = fy + bw1;
  float diff = sqrtf(t0 * t0 + t1 * t1);
  float magf = sqrtf(fx * fx + fy * fy);
  float magb = sqrtf(bw0 * bw0 + bw1 * bw1);
  float mag = 0.5f * (magf + magb);
  return (diff <= 0.01f * mag + 0.1f) ? 1.0f : 0.0f;
}

// Integer-cell first-transition outcome {xt,yt,choose} packed as u64
// (choose encoded as yt<0). Bit-identical to the verified mode-2 path.
__device__ __forceinline__ unsigned long long make_intadv(
    int pix, int piy, float fx, float fy, const float* __restrict__ bks)
{
#pragma clang fp contract(off)
  float xt = (float)pix + fx, yt = (float)piy + fy;
  Bil Bt = mkbil(xt, yt);
  const float* b0p = bks;
  const float* b1p = bks + HW;
  float o = prune_val(fx, fy,
                      b0p[Bt.i00], b0p[Bt.i01], b0p[Bt.i10], b0p[Bt.i11],
                      b1p[Bt.i00], b1p[Bt.i01], b1p[Bt.i10], b1p[Bt.i11], Bt);
  bool marg = (xt > (float)MARGIN) && (yt > (float)MARGIN) &&
              (xt < (float)(WW - MARGIN)) && (yt < (float)(HH - MARGIN));
  bool ch = marg && (o > 0.5f);
  unsigned lo = __float_as_uint(ch ? xt : 0.0f);
  unsigned hi = __float_as_uint(ch ? yt : -1.0f);
  return ((unsigned long long)hi << 32) | (unsigned long long)lo;
}

// ---------------------------------------------------------------------------
// K1: persistent scan, ONE grid barrier per step. Round-9 = round-8's
// schedule (load-free Phase A; f-gathers in the wait-window overlap) with the
// round-8 BUG fixed: the f-tap values pf0..pf7 are PERSISTENT again — they
// are consumed at the NEXT step's PRUNE_TAP both as the prune-target
// footprint offsets (mkbil(tap + f), which must match where pb was gathered)
// and as prune_val's fx/fy operands. Round 8 passed zeros there (absmax
// 1016); this restores round-7's exact dataflow while keeping the arrival
// store ahead of the scattered-gather drain.
// ---------------------------------------------------------------------------
__global__ __launch_bounds__(256, 1) void k_steps(
    const float* __restrict__ ff, const float* __restrict__ fbk,
    float* __restrict__ X, float* __restrict__ Y, float* __restrict__ Start,
    unsigned char* __restrict__ occ, unsigned long long* __restrict__ flags,
    unsigned long long* __restrict__ intadv)
{
#pragma clang fp contract(off)
  const int b = blockIdx.x;
  const int lane = threadIdx.x & 63;
  const int wv = threadIdx.x >> 6;                   // wave-in-block 0..3
  const int slot = ((wv * NBLK + b) << 6) | lane;    // wave-permuted slot id
  const unsigned long long ltmask = (1ull << lane) - 1ull;

  __shared__ unsigned long long wds[CWP];   // free-candidate bitmap (4 KB)
  __shared__ unsigned int pref[CWP];        // inclusive popcount prefix (2 KB)
  __shared__ int wsum[4];                   // scan partials
  __shared__ int wcnt[2][4];                // per-wave dead counts (parity)
  __shared__ int ps4[4];                    // per-wave lower-rank totals

  // Consumer slot state. mode: 0 dead, 1 pipelined, 2 integer-pos (pa64 valid).
  float x = 0.f, y = 0.f, st = -1.f;
  int mode = 0;
  float pf0 = 0.f, pf1 = 0.f, pf2 = 0.f, pf3 = 0.f;   // f0 at taps 00,01,10,11
  float pf4 = 0.f, pf5 = 0.f, pf6 = 0.f, pf7 = 0.f;   // f1 at taps 00,01,10,11
  float pb[32];                                        // b corner values, 8/tap
  float pxt = 0.f, pyt = 0.f;                          // advected candidate
  bool  pmarg = false;
  unsigned long long pa64 = (unsigned long long)0xBF800000u << 32;  // yt=-1

  // Producer identity (decoupled from slot): even threads, ~30 cells/wave.
  const int pj = threadIdx.x >> 1;
  const int pcell = b * CPB + pj;
  const bool prod = ((threadIdx.x & 1) == 0) && (pj < CPB) && (pcell < GG);
  int pix = 0, piy = 0, pp = 0;
  float fNx = 0.f, fNy = 0.f;      // f(s+4) pair (issued last step)
  float fCx = 0.f, fCy = 0.f;      // f(s+3) pair (arrived)
  float bC0 = 0.f, bC1 = 0.f, bC2 = 0.f, bC3 = 0.f;   // b(s+3) corners
  float bC4 = 0.f, bC5 = 0.f, bC6 = 0.f, bC7 = 0.f;

  // ---- Slot prologue: initial alive slots compute their own A(0) input ----
  if (slot < GG) {
    int ii = slot / GXC, jj = slot - ii * GXC;
    int ix = MARGIN + STEP * jj, iy = MARGIN + STEP * ii;
    x = (float)ix; y = (float)iy;
    st = 0.f; mode = 2;
    int p0_ = iy * WW + ix;
    float f0x = ff[p0_], f0y = ff[HW + p0_];
    pa64 = make_intadv(ix, iy, f0x, f0y, fbk);
  }
  X[slot] = x; Y[slot] = y;   // row 0

  // ---- Producer prologue: bootstrap intadv[1..2] + b(3)/f(4) in flight ----
  if (prod) {
    int ii = pcell / GXC, jj = pcell - ii * GXC;
    pix = MARGIN + STEP * jj; piy = MARGIN + STEP * ii;
    pp = piy * WW + pix;
    float f1x = ff[(size_t)1 * 2 * HW + pp], f1y = ff[(size_t)1 * 2 * HW + HW + pp];
    float f2x = ff[(size_t)2 * 2 * HW + pp], f2y = ff[(size_t)2 * 2 * HW + HW + pp];
    float f3x = ff[(size_t)3 * 2 * HW + pp], f3y = ff[(size_t)3 * 2 * HW + HW + pp];
    fNx = ff[(size_t)4 * 2 * HW + pp];       fNy = ff[(size_t)4 * 2 * HW + HW + pp];
    astore64(&intadv[(size_t)1 * GG + pcell],
             make_intadv(pix, piy, f1x, f1y, fbk + (size_t)1 * 2 * HW));
    astore64(&intadv[(size_t)2 * GG + pcell],
             make_intadv(pix, piy, f2x, f2y, fbk + (size_t)2 * 2 * HW));
    {  // issue b(3) corners; consumed at overlap(0)
      float xt = (float)pix + f3x, yt = (float)piy + f3y;
      Bil Bt = mkbil(xt, yt);
      const float* bb0 = fbk + (size_t)3 * 2 * HW;
      const float* bb1 = bb0 + HW;
      bC0 = bb0[Bt.i00]; bC1 = bb0[Bt.i01]; bC2 = bb0[Bt.i10]; bC3 = bb0[Bt.i11];
      bC4 = bb1[Bt.i00]; bC5 = bb1[Bt.i01]; bC6 = bb1[Bt.i10]; bC7 = bb1[Bt.i11];
      fCx = f3x; fCy = f3y;
    }
  }

// Issue the 32 b-corner loads for tap tt (consumed next iteration's A).
#define ISSUE_TAP(tt, TXI, TYI, FX, FY) do { \
    Bil Bt = mkbil((float)P.TXI + (FX), (float)P.TYI + (FY)); \
    pb[(tt)*8+0] = b0n[Bt.i00]; pb[(tt)*8+1] = b0n[Bt.i01]; \
    pb[(tt)*8+2] = b0n[Bt.i10]; pb[(tt)*8+3] = b0n[Bt.i11]; \
    pb[(tt)*8+4] = b1n[Bt.i00]; pb[(tt)*8+5] = b1n[Bt.i01]; \
    pb[(tt)*8+6] = b1n[Bt.i10]; pb[(tt)*8+7] = b1n[Bt.i11]; \
  } while (0)

// Recompute the identical footprint and fold pre-loaded values into the bit.
#define PRUNE_TAP(tt, TXI, TYI, FX, FY, OUT) do { \
    Bil Bt = mkbil((float)P.TXI + (FX), (float)P.TYI + (FY)); \
    OUT = prune_val((FX), (FY), \
                    pb[(tt)*8+0], pb[(tt)*8+1], pb[(tt)*8+2], pb[(tt)*8+3], \
                    pb[(tt)*8+4], pb[(tt)*8+5], pb[(tt)*8+6], pb[(tt)*8+7], Bt); \
  } while (0)

  for (int s = 0; s < SS - 1; ++s) {
    const unsigned char tag = (unsigned char)(s + 1);
    unsigned char* occw = occ + (((s + 1) & 1) ? OCCB : 0);   // this step's plane

    // ---- Phase A: LOAD-FREE prune decision + occ tag marks ---------------
    // pf (f at taps) and pb (b at prune targets) were gathered at
    // overlap(s-1); born lanes consume the precomputed pa64. No vmem here
    // except <=4 mark byte-stores -> barrier-entry drain is stores-only.
    bool moved = false;
    if (mode == 1) {
      Bil P = mkbil(x, y);
      float o0, o1, o2, o3;
      PRUNE_TAP(0, x0i, y0i, pf0, pf4, o0);
      PRUNE_TAP(1, x1i, y0i, pf1, pf5, o1);
      PRUNE_TAP(2, x0i, y1i, pf2, pf6, o2);
      PRUNE_TAP(3, x1i, y1i, pf3, pf7, o3);
      float fbv = ((o0 * P.w00 + o1 * P.w01) + o2 * P.w10) + o3 * P.w11;
      if (pmarg && fbv > 0.5f) {
        x = pxt; y = pyt;
        moved = true;
      } else { st = -1.f; x = 0.f; y = 0.f; mode = 0; }
    } else if (mode == 2) {
      // Integer position: precomputed outcome (pre-issued 8B load).
      float axt = __uint_as_float((unsigned)pa64);
      float ayt = __uint_as_float((unsigned)(pa64 >> 32));
      if (ayt >= 0.0f) {                      // choose
        x = axt; y = ayt; mode = 1;
        moved = true;
      } else { st = -1.f; x = 0.f; y = 0.f; mode = 0; }
    }
    if (moved) {
      int oy = (int)y, ox = (int)x;   // trunc == floor (positive)
      int i0 = ((oy - (MARGIN + 2) + 4099) >> 2) - 1024;  // ceil((oy-12)/4)
      int i1 = ((oy - (MARGIN - 2) + 4096) >> 2) - 1024;  // floor((oy-8)/4)
      int j0 = ((ox - (MARGIN + 2) + 4099) >> 2) - 1024;
      int j1 = ((ox - (MARGIN - 2) + 4096) >> 2) - 1024;
      if (i0 < 0) i0 = 0; if (i1 > GYC - 1) i1 = GYC - 1;
      if (j0 < 0) j0 = 0; if (j1 > GXC - 1) j1 = GXC - 1;
      for (int i = i0; i <= i1; ++i)
        for (int j = j0; j <= j1; ++j)
          astore8(&occw[i * GXC + j], tag);   // same-value stores: benign race
    }
    unsigned long long smask = __ballot(st < 0.0f);
    if (lane == 0) wcnt[s & 1][wv] = (int)__popcll(smask);

    // ---- Barrier arrival: entry sync drains the marks, then one store ----
    unsigned long long* fb = flags + (s & 1) * FPW;
    const int epoch = s + 1;
    __syncthreads();
    if (threadIdx.x == 0) {
      const int* wc = wcnt[s & 1];
      unsigned cpack = (unsigned)wc[0] | ((unsigned)wc[1] << 8)
                     | ((unsigned)wc[2] << 16) | ((unsigned)wc[3] << 24);
      astore64(&fb[b],
               ((unsigned long long)(unsigned)epoch << 32) | (unsigned long long)cpack);
    }

    // ---- Wait-window overlap: f-gather -> pf, advect, b-tap issue --------
    // Consumer: gather f(s+1) at (x,y) into PERSISTENT pf (consumed by
    // next A's PRUNE_TAP as footprint offsets + prune_val fx/fy), advect,
    // issue 32 b(s+1) loads at the pf-determined footprints.
    if (mode == 1 && s < SS - 2) {
      const float* f0n = ff + (size_t)(s + 1) * 2 * HW;
      const float* f1n = f0n + HW;
      Bil P = mkbil(x, y);
      pf0 = f0n[P.i00]; pf1 = f0n[P.i01]; pf2 = f0n[P.i10]; pf3 = f0n[P.i11];
      pf4 = f1n[P.i00]; pf5 = f1n[P.i01]; pf6 = f1n[P.i10]; pf7 = f1n[P.i11];
      float u_ = ((pf0 * P.w00 + pf1 * P.w01) + pf2 * P.w10) + pf3 * P.w11;
      float v_ = ((pf4 * P.w00 + pf5 * P.w01) + pf6 * P.w10) + pf7 * P.w11;
      pxt = x + u_; pyt = y + v_;
      pmarg = (pxt > (float)MARGIN) && (pyt > (float)MARGIN) &&
              (pxt < (float)(WW - MARGIN)) && (pyt < (float)(HH - MARGIN));
      const float* b0n = fbk + (size_t)(s + 1) * 2 * HW;
      const float* b1n = b0n + HW;
      ISSUE_TAP(0, x0i, y0i, pf0, pf4);
      ISSUE_TAP(1, x1i, y0i, pf1, pf5);
      ISSUE_TAP(2, x0i, y1i, pf2, pf6);
      ISSUE_TAP(3, x1i, y1i, pf3, pf7);
    }
    // Producer: compute+publish intadv[s+3]; issue b(s+4); issue f(s+5).
    if (prod) {
      if (s <= SS - 5) {                       // k = s+3 <= 30
        float xt = (float)pix + fCx, yt = (float)piy + fCy;
        Bil Bt = mkbil(xt, yt);
        float o = prune_val(fCx, fCy, bC0, bC1, bC2, bC3, bC4, bC5, bC6, bC7, Bt);
        bool marg = (xt > (float)MARGIN) && (yt > (float)MARGIN) &&
                    (xt < (float)(WW - MARGIN)) && (yt < (float)(HH - MARGIN));
        bool ch = marg && (o > 0.5f);
        unsigned lo = __float_as_uint(ch ? xt : 0.0f);
        unsigned hi = __float_as_uint(ch ? yt : -1.0f);
        astore64(&intadv[(size_t)(s + 3) * GG + pcell],
                 ((unsigned long long)hi << 32) | (unsigned long long)lo);
      }
      if (s <= SS - 6) {                       // issue b(s+4), f(s+4) arrived
        float xt = (float)pix + fNx, yt = (float)piy + fNy;
        Bil Bt = mkbil(xt, yt);
        const float* bb0 = fbk + (size_t)(s + 4) * 2 * HW;
        const float* bb1 = bb0 + HW;
        bC0 = bb0[Bt.i00]; bC1 = bb0[Bt.i01]; bC2 = bb0[Bt.i10]; bC3 = bb0[Bt.i11];
        bC4 = bb1[Bt.i00]; bC5 = bb1[Bt.i01]; bC6 = bb1[Bt.i10]; bC7 = bb1[Bt.i11];
        fCx = fNx; fCy = fNy;
      }
      if (s <= SS - 7) {                       // issue static f(s+5)
        const float* fp_ = ff + (size_t)(s + 5) * 2 * HW;
        fNx = fp_[pp]; fNy = fp_[HW + pp];
      }
    }

    // ---- Poll (wave 0): 4 loads/lane over 8 packed lines + rank prefix ---
    if (threadIdx.x < 64) {
      unsigned long long v0, v1, v2, v3;
      for (;;) {
        v0 = aload64(&fb[lane      ]);
        v1 = aload64(&fb[lane +  64]);
        v2 = aload64(&fb[lane + 128]);
        v3 = aload64(&fb[lane + 192]);
        unsigned m0 = (unsigned)(v0 >> 32), m1 = (unsigned)(v1 >> 32);
        unsigned m2 = (unsigned)(v2 >> 32), m3 = (unsigned)(v3 >> 32);
        unsigned mn = m0 < m1 ? m0 : m1;
        unsigned mn2 = m2 < m3 ? m2 : m3;
        mn = mn < mn2 ? mn : mn2;
        for (int o = 32; o > 0; o >>= 1) {
          unsigned t = (unsigned)__shfl_xor((int)mn, o, 64);
          mn = mn < t ? mn : t;
        }
        if ((int)mn >= epoch) break;
        __builtin_amdgcn_s_sleep(1);
      }
      // unpack 4x8 -> 4x16 packed u64 (field sums <= 240*64 = 15360 < 65536)
      auto up = [](unsigned long long f) -> unsigned long long {
        unsigned c = (unsigned)f;
        return (unsigned long long)(c & 0xFFu)
             | ((unsigned long long)((c >>  8) & 0xFFu) << 16)
             | ((unsigned long long)((c >> 16) & 0xFFu) << 32)
             | ((unsigned long long)((c >> 24) & 0xFFu) << 48);
      };
      unsigned long long u0 = up(v0), u1 = up(v1), u2 = up(v2), u3 = up(v3);
      unsigned long long F = u0 + u1 + u2 + u3;
      unsigned long long Pp = (lane       < b ? u0 : 0ull)
                            + (lane +  64 < b ? u1 : 0ull)
                            + (lane + 128 < b ? u2 : 0ull)
                            + (lane + 192 < b ? u3 : 0ull);
      for (int o = 32; o > 0; o >>= 1) {
        unsigned flo = (unsigned)F, fhi = (unsigned)(F >> 32);
        unsigned plo = (unsigned)Pp, phi = (unsigned)(Pp >> 32);
        unsigned flo2 = (unsigned)__shfl_xor((int)flo, o, 64);
        unsigned fhi2 = (unsigned)__shfl_xor((int)fhi, o, 64);
        unsigned plo2 = (unsigned)__shfl_xor((int)plo, o, 64);
        unsigned phi2 = (unsigned)__shfl_xor((int)phi, o, 64);
        F  += ((unsigned long long)fhi2 << 32) | flo2;
        Pp += ((unsigned long long)phi2 << 32) | plo2;
      }
      if (lane == 0) {
        int f0 = (int)(F & 0xFFFF), f1 = (int)((F >> 16) & 0xFFFF), f2 = (int)((F >> 32) & 0xFFFF);
        int p0 = (int)(Pp & 0xFFFF), p1 = (int)((Pp >> 16) & 0xFFFF);
        int p2 = (int)((Pp >> 32) & 0xFFFF), p3 = (int)((Pp >> 48) & 0xFFFF);
        ps4[0] = p0;
        ps4[1] = f0 + p1;
        ps4[2] = f0 + f1 + p2;
        ps4[3] = f0 + f1 + f2 + p3;
      }
    }
    __syncthreads();
    int ps = ps4[wv];

    // ---- Phase CD: compression, scan, births -----------------------------
    // Compression: 15 independent coalesced u64 agent loads (one exposure).
    unsigned long long cv[16];
    {
      const unsigned long long* occ64 =
          (const unsigned long long*)(occ + (((s + 1) & 1) ? OCCB : 0));
      int t = threadIdx.x;
#pragma unroll
      for (int r = 0; r < 16; ++r) {
        int j = t + 256 * r;
        cv[r] = (j < GG / 8) ? aload64(&occ64[j]) : 0ull;   // GG/8 = 3654
      }
    }
    // SWAR: byte c of cv[r] is cell 8j+c; free = byte != tag -> bit c.
    {
      unsigned char* nb = (unsigned char*)wds;
      const unsigned long long tr = 0x0101010101010101ull * (unsigned long long)tag;
      int t = threadIdx.x;
#pragma unroll
      for (int r = 0; r < 16; ++r) {
        int j = t + 256 * r;
        unsigned long long xx = cv[r] ^ tr;
        unsigned long long t1 = (xx & 0x7F7F7F7F7F7F7F7Full) + 0x7F7F7F7F7F7F7F7Full;
        unsigned long long nz = ((t1 | xx) >> 7) & 0x0101010101010101ull;
        unsigned char byte = (unsigned char)((nz * 0x0102040810204080ull) >> 56);
        nb[j] = (j < GG / 8) ? byte : (unsigned char)0;   // pads zero
      }
    }
    __syncthreads();
    // Popcount prefix over the bitmap (shuffle scan, as verified).
    {
      int t = threadIdx.x;
      int e0 = 2 * t, e1 = 2 * t + 1;
      unsigned long long m0 = wds[e0];
      unsigned long long m1 = wds[e1];
      int p0 = __popcll(m0), p1 = __popcll(m1);
      int v = p0 + p1;
      for (int o = 1; o < 64; o <<= 1) {
        int uu = __shfl_up(v, o, 64);
        if (lane >= o) v += uu;
      }
      if (lane == 63) wsum[wv] = v;
      __syncthreads();
      int base = 0;
      for (int j2 = 0; j2 < wv; ++j2) base += wsum[j2];
      pref[e0] = (unsigned int)(base + v - p1);
      pref[e1] = (unsigned int)(base + v);
      __syncthreads();
    }
    int tc = (int)pref[CWP - 1];              // total free candidates

    if (st < 0.0f) {
      int r = ps + (int)__popcll(smask & ltmask);
      if (r < tc) {                  // r < min(num_cand, num_free) <=> r < num_cand
        // word k containing rank r: largest k with pref[k-1] <= r
        int k = 0;
        for (int bb = 256; bb >= 1; bb >>= 1) {
          int nk = k + bb;
          if (nk <= CWP - 1 && (int)pref[nk - 1] <= r) k = nk;
        }
        int j = r - (k ? (int)pref[k - 1] : 0);
        unsigned long long m = wds[k];
        int lo = 0;                  // position of the (j+1)-th set bit
        for (int bb = 32; bb >= 1; bb >>= 1) {
          int nb2 = lo + bb;
          unsigned long long mask = (nb2 >= 64) ? ~0ull : ((1ull << nb2) - 1ull);
          if (__popcll(m & mask) <= j) lo = nb2;
        }
        int g = k * 64 + lo;
        int ii = g / GXC, jj = g - ii * GXC;
        x = (float)(MARGIN + STEP * jj);
        y = (float)(MARGIN + STEP * ii);
        st = (float)(s + 1);
        mode = 2;
        if (s < SS - 2)              // at s=30 there is no A(31): skip the load
          pa64 = aload64(&intadv[(size_t)(s + 1) * GG + g]);   // in flight to A(s+1)
      }
    }
    X[(size_t)(s + 1) * NSLOT + slot] = x;
    Y[(size_t)(s + 1) * NSLOT + slot] = y;
    // no trailing __syncthreads: wcnt is parity-double-buffered, and wds/pref
    // rewrites happen only after the next step's post-poll __syncthreads.
  }

#undef ISSUE_TAP
#undef PRUNE_TAP

  Start[slot] = st;
}

// ---------------------------------------------------------------------------
extern "C" void kernel_launch(void* const* d_in, const int* in_sizes, int n_in,
                              void* d_out, int out_size, void* d_ws, size_t ws_size,
                              hipStream_t stream) {
  const float* ff  = (const float*)d_in[0];   // (1,S,2,H,W)
  const float* fbk = (const float*)d_in[1];

  float* X     = (float*)d_out;                       // (S, N)
  float* Y     = X + (size_t)SS * NSLOT;              // (S, N)
  float* Start = Y + (size_t)SS * NSLOT;              // (N,)

  unsigned long long* flags  = (unsigned long long*)d_ws;             // 4 KB
  unsigned char*      occ    = (unsigned char*)(flags + 2 * FPW);     // 2 planes
  unsigned long long* intadv = (unsigned long long*)(occ + 2 * OCCB); // 31*GG u64

  k_init<<<58, 256, 0, stream>>>(flags, (unsigned int*)occ);

  k_steps<<<NBLK, 256, 0, stream>>>(ff, fbk, X, Y, Start, occ, flags, intadv);
}

// Round 10
// 385.385 us; speedup vs baseline: 3.5686x; 1.0734x over previous
//
#include <hip/hip_runtime.h>
#include <cstdint>

// Problem constants (fixed by setup_inputs: H=480, W=1024, S=32, margin=10, step=4)
#define HH 480
#define WW 1024
#define SS 32
#define HW (HH*WW)              // 491520
#define MARGIN 10
#define STEP 4
#define GYC 116                 // len(arange(10, 471, 4))
#define GXC 252                 // len(arange(10, 1015, 4))
#define GG (GYC*GXC)            // 29232 grid candidates (= 456*64 + 48)
#define NSLOT (2*HH*WW/(STEP*STEP))  // 61440 trajectory slots
#define NBLK (NSLOT/256)        // 240 blocks -> co-resident on 256 CUs
#define CW ((GG+63)/64)         // 457 candidate bitmap words
#define CWP 512                 // padded word count (per-block scan width + plane stride)
#define FPW 256                 // u64 flag entries per parity plane (packed, 8 lines)
#define CPB 122                 // producer cells per block (240*122 >= GG)

// Agent-scope (device-coherent) accessors.
__device__ __forceinline__ unsigned long long aload64(const unsigned long long* p) {
  return __hip_atomic_load(p, __ATOMIC_RELAXED, __HIP_MEMORY_SCOPE_AGENT);
}
__device__ __forceinline__ void astore64(unsigned long long* p, unsigned long long v) {
  __hip_atomic_store(p, v, __ATOMIC_RELAXED, __HIP_MEMORY_SCOPE_AGENT);
}
__device__ __forceinline__ void aor64(unsigned long long* p, unsigned long long v) {
  (void)__hip_atomic_fetch_or(p, v, __ATOMIC_RELAXED, __HIP_MEMORY_SCOPE_AGENT);
}

__device__ __forceinline__ int clampi(int v, int lo, int hi) {
  return v < lo ? lo : (v > hi ? hi : v);
}

// Paired corner load: bilinear footprints always read cols (x0i, x1i) with
// x1i = min(x0i+1, WW-1). One unaligned 8B load at bx = min(x0i, WW-2) gives
// v = (base[row*WW+bx], base[row*WW+bx+1]); then
//   c0 = base[row*WW+x0i] = (x0i==bx) ? v.x : v.y   (x0i=WW-1 -> bx+1)
//   c1 = base[row*WW+x1i] = v.y                      (x1i = bx+1 in ALL cases)
// Values bit-identical to the two scalar loads; halves gather instructions.
__device__ __forceinline__ void ld2(const float* __restrict__ base, int row, int xlo,
                                    float& c0, float& c1) {
  int bx = (xlo < WW - 1) ? xlo : (WW - 2);
  float2 v;
  __builtin_memcpy(&v, base + row * WW + bx, 8);
  c0 = (xlo == bx) ? v.x : v.y;
  c1 = v.y;
}

// ---------------------------------------------------------------------------
// K0: zero the 32 occupancy bit-planes + init both parity flag planes.
// ---------------------------------------------------------------------------
__global__ __launch_bounds__(256) void k_init(unsigned long long* __restrict__ flags,
                                              unsigned int* __restrict__ bmp32)
{
  int idx = blockIdx.x * 256 + threadIdx.x;
  if (idx < 32 * CWP * 2) bmp32[idx] = 0u;           // 32 planes x 512 u64
  if (idx < 256) {
    unsigned long long v = (idx < NBLK) ? 0ull : (0x7FFFFFFFull << 32); // pads: +inf
    flags[idx] = v;
    flags[FPW + idx] = v;
  }
}

// ---------------------------------------------------------------------------
// Bilinear footprint at (xs,ys). Identical float ops to the verified kernels.
// ---------------------------------------------------------------------------
struct Bil {
  int x0i, x1i, y0i, y1i;
  int i00, i01, i10, i11;
  float w00, w01, w10, w11;
};

__device__ __forceinline__ Bil mkbil(float xs, float ys) {
#pragma clang fp contract(off)
  float x0 = floorf(xs), y0 = floorf(ys);
  float wx1 = xs - x0, wx0 = 1.0f - wx1;
  float wy1 = ys - y0, wy0 = 1.0f - wy1;
  Bil b;
  b.x0i = clampi((int)x0, 0, WW - 1);
  b.x1i = b.x0i + 1 > WW - 1 ? WW - 1 : b.x0i + 1;
  b.y0i = clampi((int)y0, 0, HH - 1);
  b.y1i = b.y0i + 1 > HH - 1 ? HH - 1 : b.y0i + 1;
  b.i00 = b.y0i * WW + b.x0i; b.i01 = b.y0i * WW + b.x1i;
  b.i10 = b.y1i * WW + b.x0i; b.i11 = b.y1i * WW + b.x1i;
  b.w00 = wy0 * wx0; b.w01 = wy0 * wx1;
  b.w10 = wy1 * wx0; b.w11 = wy1 * wx1;
  return b;
}

// Fwd-bwd consistency bit from pre-gathered backward-flow corner values.
__device__ __forceinline__ float prune_val(float fx, float fy,
    float c00a, float c01a, float c10a, float c11a,
    float c00b, float c01b, float c10b, float c11b, const Bil& t)
{
#pragma clang fp contract(off)
  float bw0 = ((c00a * t.w00 + c01a * t.w01) + c10a * t.w10) + c11a * t.w11;
  float bw1 = ((c00b * t.w00 + c01b * t.w01) + c10b * t.w10) + c11b * t.w11;
  float t0 = fx + bw0, t1 = fy + bw1;
  float diff = sqrtf(t0 * t0 + t1 * t1);
  float magf = sqrtf(fx * fx + fy * fy);
  float magb = sqrtf(bw0 * bw0 + bw1 * bw1);
  float mag = 0.5f * (magf + magb);
  return (diff <= 0.01f * mag + 0.1f) ? 1.0f : 0.0f;
}

// Integer-cell first-transition outcome {xt,yt,choose} packed as u64
// (choose encoded as yt<0). Bit-identical to the verified mode-2 path.
__device__ __forceinline__ unsigned long long make_intadv(
    int pix, int piy, float fx, float fy, const float* __restrict__ bks)
{
#pragma clang fp contract(off)
  float xt = (float)pix + fx, yt = (float)piy + fy;
  Bil Bt = mkbil(xt, yt);
  const float* b0p = bks;
  const float* b1p = bks + HW;
  float o = prune_val(fx, fy,
                      b0p[Bt.i00], b0p[Bt.i01], b0p[Bt.i10], b0p[Bt.i11],
                      b1p[Bt.i00], b1p[Bt.i01], b1p[Bt.i10], b1p[Bt.i11], Bt);
  bool marg = (xt > (float)MARGIN) && (yt > (float)MARGIN) &&
              (xt < (float)(WW - MARGIN)) && (yt < (float)(HH - MARGIN));
  bool ch = marg && (o > 0.5f);
  unsigned lo = __float_as_uint(ch ? xt : 0.0f);
  unsigned hi = __float_as_uint(ch ? yt : -1.0f);
  return ((unsigned long long)hi << 32) | (unsigned long long)lo;
}

// ---------------------------------------------------------------------------
// K1: persistent scan, ONE grid barrier per step. Round-10 changes (prune
// arithmetic and ordering byte-identical; only load WIDTH and occ REP move):
//  * PAIRED CORNER LOADS (ld2): every footprint row-pair is one 8B load.
//    TA line-request cost was the dominant term (~2.2 us/step: 40 divergent
//    gathers x 64 lanes); now 20 gathers/lane. Border clamp handled exactly.
//  * BIT-PLANE OCCUPANCY: 31 pre-zeroed u64 planes (plane s+1 per step);
//    marks are <=4 memory-side atomic ORs; the 15-load+SWAR compression is
//    deleted — the prefix pass directly loads 2 masked words/thread.
// ---------------------------------------------------------------------------
__global__ __launch_bounds__(256, 1) void k_steps(
    const float* __restrict__ ff, const float* __restrict__ fbk,
    float* __restrict__ X, float* __restrict__ Y, float* __restrict__ Start,
    unsigned long long* __restrict__ bmp, unsigned long long* __restrict__ flags,
    unsigned long long* __restrict__ intadv)
{
#pragma clang fp contract(off)
  const int b = blockIdx.x;
  const int lane = threadIdx.x & 63;
  const int wv = threadIdx.x >> 6;                   // wave-in-block 0..3
  const int slot = ((wv * NBLK + b) << 6) | lane;    // wave-permuted slot id
  const unsigned long long ltmask = (1ull << lane) - 1ull;

  __shared__ unsigned long long wds[CWP];   // free-candidate bitmap (4 KB)
  __shared__ unsigned int pref[CWP];        // inclusive popcount prefix (2 KB)
  __shared__ int wsum[4];                   // scan partials
  __shared__ int wcnt[2][4];                // per-wave dead counts (parity)
  __shared__ int ps4[4];                    // per-wave lower-rank totals

  // Consumer slot state. mode: 0 dead, 1 pipelined, 2 integer-pos (pa64 valid).
  float x = 0.f, y = 0.f, st = -1.f;
  int mode = 0;
  float pf0 = 0.f, pf1 = 0.f, pf2 = 0.f, pf3 = 0.f;   // f0 at taps 00,01,10,11
  float pf4 = 0.f, pf5 = 0.f, pf6 = 0.f, pf7 = 0.f;   // f1 at taps 00,01,10,11
  float pb[32];                                        // b corner values, 8/tap
  float pxt = 0.f, pyt = 0.f;                          // advected candidate
  bool  pmarg = false;
  unsigned long long pa64 = (unsigned long long)0xBF800000u << 32;  // yt=-1

  // Producer identity (decoupled from slot): even threads, ~30 cells/wave.
  const int pj = threadIdx.x >> 1;
  const int pcell = b * CPB + pj;
  const bool prod = ((threadIdx.x & 1) == 0) && (pj < CPB) && (pcell < GG);
  int pix = 0, piy = 0, pp = 0;
  float fNx = 0.f, fNy = 0.f;      // f(s+4) pair (issued last step)
  float fCx = 0.f, fCy = 0.f;      // f(s+3) pair (arrived)
  float bC0 = 0.f, bC1 = 0.f, bC2 = 0.f, bC3 = 0.f;   // b(s+3) corners
  float bC4 = 0.f, bC5 = 0.f, bC6 = 0.f, bC7 = 0.f;

  // ---- Slot prologue: initial alive slots compute their own A(0) input ----
  if (slot < GG) {
    int ii = slot / GXC, jj = slot - ii * GXC;
    int ix = MARGIN + STEP * jj, iy = MARGIN + STEP * ii;
    x = (float)ix; y = (float)iy;
    st = 0.f; mode = 2;
    int p0_ = iy * WW + ix;
    float f0x = ff[p0_], f0y = ff[HW + p0_];
    pa64 = make_intadv(ix, iy, f0x, f0y, fbk);
  }
  X[slot] = x; Y[slot] = y;   // row 0

  // ---- Producer prologue: bootstrap intadv[1..2] + b(3)/f(4) in flight ----
  if (prod) {
    int ii = pcell / GXC, jj = pcell - ii * GXC;
    pix = MARGIN + STEP * jj; piy = MARGIN + STEP * ii;
    pp = piy * WW + pix;
    float f1x = ff[(size_t)1 * 2 * HW + pp], f1y = ff[(size_t)1 * 2 * HW + HW + pp];
    float f2x = ff[(size_t)2 * 2 * HW + pp], f2y = ff[(size_t)2 * 2 * HW + HW + pp];
    float f3x = ff[(size_t)3 * 2 * HW + pp], f3y = ff[(size_t)3 * 2 * HW + HW + pp];
    fNx = ff[(size_t)4 * 2 * HW + pp];       fNy = ff[(size_t)4 * 2 * HW + HW + pp];
    astore64(&intadv[(size_t)1 * GG + pcell],
             make_intadv(pix, piy, f1x, f1y, fbk + (size_t)1 * 2 * HW));
    astore64(&intadv[(size_t)2 * GG + pcell],
             make_intadv(pix, piy, f2x, f2y, fbk + (size_t)2 * 2 * HW));
    {  // issue b(3) corners; consumed at overlap(0)
      float xt = (float)pix + f3x, yt = (float)piy + f3y;
      Bil Bt = mkbil(xt, yt);
      const float* bb0 = fbk + (size_t)3 * 2 * HW;
      const float* bb1 = bb0 + HW;
      ld2(bb0, Bt.y0i, Bt.x0i, bC0, bC1);
      ld2(bb0, Bt.y1i, Bt.x0i, bC2, bC3);
      ld2(bb1, Bt.y0i, Bt.x0i, bC4, bC5);
      ld2(bb1, Bt.y1i, Bt.x0i, bC6, bC7);
      fCx = f3x; fCy = f3y;
    }
  }

// Issue the 16 paired b-corner loads for tap tt (consumed next step's A).
#define ISSUE_TAP(tt, TXI, TYI, FX, FY) do { \
    Bil Bt = mkbil((float)P.TXI + (FX), (float)P.TYI + (FY)); \
    ld2(b0n, Bt.y0i, Bt.x0i, pb[(tt)*8+0], pb[(tt)*8+1]); \
    ld2(b0n, Bt.y1i, Bt.x0i, pb[(tt)*8+2], pb[(tt)*8+3]); \
    ld2(b1n, Bt.y0i, Bt.x0i, pb[(tt)*8+4], pb[(tt)*8+5]); \
    ld2(b1n, Bt.y1i, Bt.x0i, pb[(tt)*8+6], pb[(tt)*8+7]); \
  } while (0)

// Recompute the identical footprint and fold pre-loaded values into the bit.
#define PRUNE_TAP(tt, TXI, TYI, FX, FY, OUT) do { \
    Bil Bt = mkbil((float)P.TXI + (FX), (float)P.TYI + (FY)); \
    OUT = prune_val((FX), (FY), \
                    pb[(tt)*8+0], pb[(tt)*8+1], pb[(tt)*8+2], pb[(tt)*8+3], \
                    pb[(tt)*8+4], pb[(tt)*8+5], pb[(tt)*8+6], pb[(tt)*8+7], Bt); \
  } while (0)

  for (int s = 0; s < SS - 1; ++s) {
    unsigned long long* pl = bmp + (size_t)(s + 1) * CWP;   // this step's bit-plane

    // ---- Phase A: LOAD-FREE prune decision + bit-plane marks -------------
    bool moved = false;
    if (mode == 1) {
      Bil P = mkbil(x, y);
      float o0, o1, o2, o3;
      PRUNE_TAP(0, x0i, y0i, pf0, pf4, o0);
      PRUNE_TAP(1, x1i, y0i, pf1, pf5, o1);
      PRUNE_TAP(2, x0i, y1i, pf2, pf6, o2);
      PRUNE_TAP(3, x1i, y1i, pf3, pf7, o3);
      float fbv = ((o0 * P.w00 + o1 * P.w01) + o2 * P.w10) + o3 * P.w11;
      if (pmarg && fbv > 0.5f) {
        x = pxt; y = pyt;
        moved = true;
      } else { st = -1.f; x = 0.f; y = 0.f; mode = 0; }
    } else if (mode == 2) {
      float axt = __uint_as_float((unsigned)pa64);
      float ayt = __uint_as_float((unsigned)(pa64 >> 32));
      if (ayt >= 0.0f) {                      // choose
        x = axt; y = ayt; mode = 1;
        moved = true;
      } else { st = -1.f; x = 0.f; y = 0.f; mode = 0; }
    }
    if (moved) {
      int oy = (int)y, ox = (int)x;   // trunc == floor (positive)
      int i0 = ((oy - (MARGIN + 2) + 4099) >> 2) - 1024;  // ceil((oy-12)/4)
      int i1 = ((oy - (MARGIN - 2) + 4096) >> 2) - 1024;  // floor((oy-8)/4)
      int j0 = ((ox - (MARGIN + 2) + 4099) >> 2) - 1024;
      int j1 = ((ox - (MARGIN - 2) + 4096) >> 2) - 1024;
      if (i0 < 0) i0 = 0; if (i1 > GYC - 1) i1 = GYC - 1;
      if (j0 < 0) j0 = 0; if (j1 > GXC - 1) j1 = GXC - 1;
      for (int i = i0; i <= i1; ++i) {        // <=2 rows, <=2 adjacent bits
        int g0 = i * GXC + j0;
        int w = g0 >> 6, bo = g0 & 63;
        unsigned long long m = ((j1 > j0) ? 3ull : 1ull) << bo;  // bit63 ovfl drops
        aor64(&pl[w], m);
        if (bo == 63 && j1 > j0) aor64(&pl[w + 1], 1ull);
      }
    }
    unsigned long long smask = __ballot(st < 0.0f);
    if (lane == 0) wcnt[s & 1][wv] = (int)__popcll(smask);

    // ---- Barrier arrival: entry sync drains the marks, then one store ----
    unsigned long long* fb = flags + (s & 1) * FPW;
    const int epoch = s + 1;
    __syncthreads();
    if (threadIdx.x == 0) {
      const int* wc = wcnt[s & 1];
      unsigned cpack = (unsigned)wc[0] | ((unsigned)wc[1] << 8)
                     | ((unsigned)wc[2] << 16) | ((unsigned)wc[3] << 24);
      astore64(&fb[b],
               ((unsigned long long)(unsigned)epoch << 32) | (unsigned long long)cpack);
    }

    // ---- Wait-window overlap: f-gather -> pf, advect, b-tap issue --------
    if (mode == 1 && s < SS - 2) {
      const float* f0n = ff + (size_t)(s + 1) * 2 * HW;
      const float* f1n = f0n + HW;
      Bil P = mkbil(x, y);
      ld2(f0n, P.y0i, P.x0i, pf0, pf1);
      ld2(f0n, P.y1i, P.x0i, pf2, pf3);
      ld2(f1n, P.y0i, P.x0i, pf4, pf5);
      ld2(f1n, P.y1i, P.x0i, pf6, pf7);
      float u_ = ((pf0 * P.w00 + pf1 * P.w01) + pf2 * P.w10) + pf3 * P.w11;
      float v_ = ((pf4 * P.w00 + pf5 * P.w01) + pf6 * P.w10) + pf7 * P.w11;
      pxt = x + u_; pyt = y + v_;
      pmarg = (pxt > (float)MARGIN) && (pyt > (float)MARGIN) &&
              (pxt < (float)(WW - MARGIN)) && (pyt < (float)(HH - MARGIN));
      const float* b0n = fbk + (size_t)(s + 1) * 2 * HW;
      const float* b1n = b0n + HW;
      ISSUE_TAP(0, x0i, y0i, pf0, pf4);
      ISSUE_TAP(1, x1i, y0i, pf1, pf5);
      ISSUE_TAP(2, x0i, y1i, pf2, pf6);
      ISSUE_TAP(3, x1i, y1i, pf3, pf7);
    }
    // Producer: compute+publish intadv[s+3]; issue b(s+4); issue f(s+5).
    if (prod) {
      if (s <= SS - 5) {                       // k = s+3 <= 30
        float xt = (float)pix + fCx, yt = (float)piy + fCy;
        Bil Bt = mkbil(xt, yt);
        float o = prune_val(fCx, fCy, bC0, bC1, bC2, bC3, bC4, bC5, bC6, bC7, Bt);
        bool marg = (xt > (float)MARGIN) && (yt > (float)MARGIN) &&
                    (xt < (float)(WW - MARGIN)) && (yt < (float)(HH - MARGIN));
        bool ch = marg && (o > 0.5f);
        unsigned lo = __float_as_uint(ch ? xt : 0.0f);
        unsigned hi = __float_as_uint(ch ? yt : -1.0f);
        astore64(&intadv[(size_t)(s + 3) * GG + pcell],
                 ((unsigned long long)hi << 32) | (unsigned long long)lo);
      }
      if (s <= SS - 6) {                       // issue b(s+4), f(s+4) arrived
        float xt = (float)pix + fNx, yt = (float)piy + fNy;
        Bil Bt = mkbil(xt, yt);
        const float* bb0 = fbk + (size_t)(s + 4) * 2 * HW;
        const float* bb1 = bb0 + HW;
        ld2(bb0, Bt.y0i, Bt.x0i, bC0, bC1);
        ld2(bb0, Bt.y1i, Bt.x0i, bC2, bC3);
        ld2(bb1, Bt.y0i, Bt.x0i, bC4, bC5);
        ld2(bb1, Bt.y1i, Bt.x0i, bC6, bC7);
        fCx = fNx; fCy = fNy;
      }
      if (s <= SS - 7) {                       // issue static f(s+5)
        const float* fp_ = ff + (size_t)(s + 5) * 2 * HW;
        fNx = fp_[pp]; fNy = fp_[HW + pp];
      }
    }

    // ---- Poll (wave 0): 4 loads/lane over 8 packed lines + rank prefix ---
    if (threadIdx.x < 64) {
      unsigned long long v0, v1, v2, v3;
      for (;;) {
        v0 = aload64(&fb[lane      ]);
        v1 = aload64(&fb[lane +  64]);
        v2 = aload64(&fb[lane + 128]);
        v3 = aload64(&fb[lane + 192]);
        unsigned m0 = (unsigned)(v0 >> 32), m1 = (unsigned)(v1 >> 32);
        unsigned m2 = (unsigned)(v2 >> 32), m3 = (unsigned)(v3 >> 32);
        unsigned mn = m0 < m1 ? m0 : m1;
        unsigned mn2 = m2 < m3 ? m2 : m3;
        mn = mn < mn2 ? mn : mn2;
        for (int o = 32; o > 0; o >>= 1) {
          unsigned t = (unsigned)__shfl_xor((int)mn, o, 64);
          mn = mn < t ? mn : t;
        }
        if ((int)mn >= epoch) break;
        __builtin_amdgcn_s_sleep(1);
      }
      auto up = [](unsigned long long f) -> unsigned long long {
        unsigned c = (unsigned)f;
        return (unsigned long long)(c & 0xFFu)
             | ((unsigned long long)((c >>  8) & 0xFFu) << 16)
             | ((unsigned long long)((c >> 16) & 0xFFu) << 32)
             | ((unsigned long long)((c >> 24) & 0xFFu) << 48);
      };
      unsigned long long u0 = up(v0), u1 = up(v1), u2 = up(v2), u3 = up(v3);
      unsigned long long F = u0 + u1 + u2 + u3;
      unsigned long long Pp = (lane       < b ? u0 : 0ull)
                            + (lane +  64 < b ? u1 : 0ull)
                            + (lane + 128 < b ? u2 : 0ull)
                            + (lane + 192 < b ? u3 : 0ull);
      for (int o = 32; o > 0; o >>= 1) {
        unsigned flo = (unsigned)F, fhi = (unsigned)(F >> 32);
        unsigned plo = (unsigned)Pp, phi = (unsigned)(Pp >> 32);
        unsigned flo2 = (unsigned)__shfl_xor((int)flo, o, 64);
        unsigned fhi2 = (unsigned)__shfl_xor((int)fhi, o, 64);
        unsigned plo2 = (unsigned)__shfl_xor((int)plo, o, 64);
        unsigned phi2 = (unsigned)__shfl_xor((int)phi, o, 64);
        F  += ((unsigned long long)fhi2 << 32) | flo2;
        Pp += ((unsigned long long)phi2 << 32) | plo2;
      }
      if (lane == 0) {
        int f0 = (int)(F & 0xFFFF), f1 = (int)((F >> 16) & 0xFFFF), f2 = (int)((F >> 32) & 0xFFFF);
        int p0 = (int)(Pp & 0xFFFF), p1 = (int)((Pp >> 16) & 0xFFFF);
        int p2 = (int)((Pp >> 32) & 0xFFFF), p3 = (int)((Pp >> 48) & 0xFFFF);
        ps4[0] = p0;
        ps4[1] = f0 + p1;
        ps4[2] = f0 + f1 + p2;
        ps4[3] = f0 + f1 + f2 + p3;
      }
    }
    __syncthreads();
    int ps = ps4[wv];

    // ---- Phase CD: direct masked bit-plane load + prefix + births --------
    {
      int t = threadIdx.x;
      int e0 = 2 * t, e1 = 2 * t + 1;
      unsigned long long m0 = 0ull, m1 = 0ull;
      if (e0 < CW) m0 = ~aload64(&pl[e0]);            // free = NOT occupied
      if (e1 < CW) m1 = ~aload64(&pl[e1]);
      if (e0 == CW - 1) m0 &= (1ull << 48) - 1ull;    // tail: 48 valid cells
      if (e1 == CW - 1) m1 &= (1ull << 48) - 1ull;
      wds[e0] = m0; wds[e1] = m1;
      int p0 = __popcll(m0), p1 = __popcll(m1);
      int v = p0 + p1;
      for (int o = 1; o < 64; o <<= 1) {
        int uu = __shfl_up(v, o, 64);
        if (lane >= o) v += uu;
      }
      if (lane == 63) wsum[wv] = v;
      __syncthreads();
      int base = 0;
      for (int j2 = 0; j2 < wv; ++j2) base += wsum[j2];
      pref[e0] = (unsigned int)(base + v - p1);
      pref[e1] = (unsigned int)(base + v);
      __syncthreads();
    }
    int tc = (int)pref[CWP - 1];              // total free candidates

    if (st < 0.0f) {
      int r = ps + (int)__popcll(smask & ltmask);
      if (r < tc) {                  // r < min(num_cand, num_free) <=> r < num_cand
        int k = 0;
        for (int bb = 256; bb >= 1; bb >>= 1) {
          int nk = k + bb;
          if (nk <= CWP - 1 && (int)pref[nk - 1] <= r) k = nk;
        }
        int j = r - (k ? (int)pref[k - 1] : 0);
        unsigned long long m = wds[k];
        int lo = 0;                  // position of the (j+1)-th set bit
        for (int bb = 32; bb >= 1; bb >>= 1) {
          int nb2 = lo + bb;
          unsigned long long mask = (nb2 >= 64) ? ~0ull : ((1ull << nb2) - 1ull);
          if (__popcll(m & mask) <= j) lo = nb2;
        }
        int g = k * 64 + lo;
        int ii = g / GXC, jj = g - ii * GXC;
        x = (float)(MARGIN + STEP * jj);
        y = (float)(MARGIN + STEP * ii);
        st = (float)(s + 1);
        mode = 2;
        if (s < SS - 2)              // at s=30 there is no A(31): skip the load
          pa64 = aload64(&intadv[(size_t)(s + 1) * GG + g]);   // in flight to A(s+1)
      }
    }
    X[(size_t)(s + 1) * NSLOT + slot] = x;
    Y[(size_t)(s + 1) * NSLOT + slot] = y;
    // no trailing __syncthreads: wcnt is parity-double-buffered, and wds/pref
    // rewrites happen only after the next step's post-poll __syncthreads.
  }

#undef ISSUE_TAP
#undef PRUNE_TAP

  Start[slot] = st;
}

// ---------------------------------------------------------------------------
extern "C" void kernel_launch(void* const* d_in, const int* in_sizes, int n_in,
                              void* d_out, int out_size, void* d_ws, size_t ws_size,
                              hipStream_t stream) {
  const float* ff  = (const float*)d_in[0];   // (1,S,2,H,W)
  const float* fbk = (const float*)d_in[1];

  float* X     = (float*)d_out;                       // (S, N)
  float* Y     = X + (size_t)SS * NSLOT;              // (S, N)
  float* Start = Y + (size_t)SS * NSLOT;              // (N,)

  unsigned long long* flags  = (unsigned long long*)d_ws;              // 4 KB
  unsigned long long* bmp    = flags + 2 * FPW;                        // 32 planes x 512 u64
  unsigned long long* intadv = bmp + 32 * CWP;                         // 31*GG u64

  k_init<<<128, 256, 0, stream>>>(flags, (unsigned int*)bmp);

  k_steps<<<NBLK, 256, 0, stream>>>(ff, fbk, X, Y, Start, bmp, flags, intadv);
}